// Round 4
// baseline (1149.126 us; speedup 1.0000x reference)
//
#include <hip/hip_runtime.h>
#include <math.h>

// Problem constants (from reference)
#define N_NODES 40000
#define N_EDGES 640000
#define F_IN    1280
#define H       128
#define NG      64
#define OUTD    273
#define FC1D    1024
#define NEG_SLOPE 0.2f
#define BN_EPS  1e-5f

typedef __attribute__((ext_vector_type(8))) short short8;
typedef __attribute__((ext_vector_type(4))) float f32x4;

// fp32 -> bf16 (RNE) and back, as bit patterns
__device__ __forceinline__ unsigned short f2bf(float f) {
    unsigned u = __float_as_uint(f);
    u += 0x7FFF + ((u >> 16) & 1);
    return (unsigned short)(u >> 16);
}
__device__ __forceinline__ float bf2f(unsigned short s) {
    return __uint_as_float((unsigned)s << 16);
}

// ---------------------------------------------------------------------------
// CSR build: histogram -> exclusive scan -> fill
// ---------------------------------------------------------------------------
__global__ void edge_hist(const int* __restrict__ dst, int* __restrict__ cnt, int e) {
    int i = blockIdx.x * blockDim.x + threadIdx.x;
    if (i < e) atomicAdd(&cnt[dst[i]], 1);
}

__global__ void scan_excl(const int* __restrict__ cnt, int* __restrict__ row_ptr, int n) {
    const int CH = 40;                      // 1024*40 = 40960 >= 40000
    __shared__ int sm[1024];
    int tid = threadIdx.x;
    int start = tid * CH;
    int local[CH];
    int s = 0;
    #pragma unroll
    for (int k = 0; k < CH; ++k) {
        int i = start + k;
        int v = (i < n) ? cnt[i] : 0;
        local[k] = s;
        s += v;
    }
    sm[tid] = s;
    __syncthreads();
    for (int off = 1; off < 1024; off <<= 1) {
        int t = (tid >= off) ? sm[tid - off] : 0;
        __syncthreads();
        sm[tid] += t;
        __syncthreads();
    }
    int base = sm[tid] - s;
    #pragma unroll
    for (int k = 0; k < CH; ++k) {
        int i = start + k;
        if (i < n) row_ptr[i] = base + local[k];
    }
    if (tid == 1023) row_ptr[n] = sm[1023];
}

__global__ void edge_fill(const int* __restrict__ src, const int* __restrict__ dst,
                          const int* __restrict__ row_ptr, int* __restrict__ fill,
                          int* __restrict__ csr_src, int e) {
    int i = blockIdx.x * blockDim.x + threadIdx.x;
    if (i < e) {
        int d = dst[i];
        int pos = row_ptr[d] + atomicAdd(&fill[d], 1);
        csr_src[pos] = src[i];
    }
}

// ---------------------------------------------------------------------------
// weight prep: W[K][128] fp32  ->  Wt_hi[128][K], Wt_lo[128][K] (bf16 split)
// ---------------------------------------------------------------------------
__global__ void wprep(const float* __restrict__ W, unsigned short* __restrict__ Wth,
                      unsigned short* __restrict__ Wtl, int K) {
    int i = blockIdx.x * blockDim.x + threadIdx.x;
    if (i >= K * H) return;
    int k = i >> 7, n = i & 127;
    float v = W[i];
    unsigned short h = f2bf(v);
    float r = v - bf2f(h);
    Wth[(size_t)n * K + k] = h;
    Wtl[(size_t)n * K + k] = f2bf(r);
}

// ---------------------------------------------------------------------------
// GEMM bf16x3 MFMA v2: C[M,128] = A[M,K] @ B[K,128]
//  - A: fp32 global -> registers -> hi/lo bf16 fragments (NO LDS for A)
//  - B: staged per BK=64 chunk in *fragment layout* LDS (linear, conflict-free),
//       register-prefetched one chunk ahead (T14 async-stage split)
//  - BM=64, 256 threads = 4 waves, each wave: 16 rows x 128 cols (8 N-frags)
//  M multiple of 64, K multiple of 64.
// ---------------------------------------------------------------------------
#define GBK 64

__device__ __forceinline__ void cvt8(float4 x, float4 y, short8& hi, short8& lo) {
    float f[8] = {x.x, x.y, x.z, x.w, y.x, y.y, y.z, y.w};
    #pragma unroll
    for (int j = 0; j < 8; ++j) {
        unsigned u = __float_as_uint(f[j]);
        unsigned short hh = (unsigned short)((u + 0x7FFF + ((u >> 16) & 1)) >> 16);
        hi[j] = (short)hh;
        float r = f[j] - __uint_as_float((unsigned)hh << 16);
        unsigned ur = __float_as_uint(r);
        lo[j] = (short)((ur + 0x7FFF + ((ur >> 16) & 1)) >> 16);
    }
}

__global__ __launch_bounds__(256) void gemm_mfma(
    const float* __restrict__ A, const unsigned short* __restrict__ Bth,
    const unsigned short* __restrict__ Btl, float* __restrict__ C, int K)
{
    // fragment-layout B: hi slots [0,8192) shorts, lo slots [8192,16384)
    // slot(n,s,lane) = ((n*2+s)*64 + lane), 16B per slot
    __shared__ unsigned short lds[16384];          // 32 KB
    const int tid  = threadIdx.x;
    const int lane = tid & 63, wv = tid >> 6;
    const int fr = lane & 15, q = lane >> 4;
    const int m0 = blockIdx.x * 64;
    const int row = m0 + wv * 16 + fr;

    // ---- staging map: 8 units/thread; unit u = tid + 256*r ----
    // u<1024: hi, else lo. within: col = (u&1023)>>3, kkg = u&7 (k = kkg*8)
    const unsigned short* srcP[8];
    int dstOff[8];                                  // in shorts
    #pragma unroll
    for (int r = 0; r < 8; ++r) {
        int u = tid + 256 * r;
        int lo_ = u >> 10;
        int v = u & 1023;
        int col = v >> 3, kkg = v & 7;
        srcP[r] = (lo_ ? Btl : Bth) + (size_t)col * K + kkg * 8;
        int slot = ((col >> 4) * 2 + (kkg >> 2)) * 64 + (kkg & 3) * 16 + (col & 15);
        dstOff[r] = lo_ * 8192 + slot * 8;
    }

    const int nt = K / GBK;
    uint4 pref[8];
    #pragma unroll
    for (int r = 0; r < 8; ++r) pref[r] = *(const uint4*)(srcP[r]);   // chunk 0

    f32x4 acc[8] = {};

    for (int t = 0; t < nt; ++t) {
        // write staged chunk t (compiler inserts vmcnt wait before use)
        #pragma unroll
        for (int r = 0; r < 8; ++r) *(uint4*)&lds[dstOff[r]] = pref[r];
        // issue chunk t+1 loads (latency hides under compute below)
        if (t + 1 < nt) {
            #pragma unroll
            for (int r = 0; r < 8; ++r)
                pref[r] = *(const uint4*)(srcP[r] + (t + 1) * GBK);
        }
        __syncthreads();

        // A fragments straight from global (2 k-subtiles of 32)
        const float* ap = A + (size_t)row * K + t * GBK + q * 8;
        float4 a0 = *(const float4*)(ap);
        float4 a1 = *(const float4*)(ap + 4);
        float4 a2 = *(const float4*)(ap + 32);
        float4 a3 = *(const float4*)(ap + 36);

        short8 ah, al;
        cvt8(a0, a1, ah, al);
        #pragma unroll
        for (int n = 0; n < 8; ++n) {
            int sl = ((n * 2 + 0) * 64 + lane) * 8;
            short8 bh = *(const short8*)&lds[sl];
            short8 bl = *(const short8*)&lds[sl + 8192];
            acc[n] = __builtin_amdgcn_mfma_f32_16x16x32_bf16(ah, bh, acc[n], 0, 0, 0);
            acc[n] = __builtin_amdgcn_mfma_f32_16x16x32_bf16(ah, bl, acc[n], 0, 0, 0);
            acc[n] = __builtin_amdgcn_mfma_f32_16x16x32_bf16(al, bh, acc[n], 0, 0, 0);
        }
        cvt8(a2, a3, ah, al);
        #pragma unroll
        for (int n = 0; n < 8; ++n) {
            int sl = ((n * 2 + 1) * 64 + lane) * 8;
            short8 bh = *(const short8*)&lds[sl];
            short8 bl = *(const short8*)&lds[sl + 8192];
            acc[n] = __builtin_amdgcn_mfma_f32_16x16x32_bf16(ah, bh, acc[n], 0, 0, 0);
            acc[n] = __builtin_amdgcn_mfma_f32_16x16x32_bf16(ah, bl, acc[n], 0, 0, 0);
            acc[n] = __builtin_amdgcn_mfma_f32_16x16x32_bf16(al, bh, acc[n], 0, 0, 0);
        }
        __syncthreads();
    }

    // epilogue: C/D layout col=lane&15, row=(lane>>4)*4+i  [m89]
    const int rb = m0 + wv * 16 + q * 4;
    #pragma unroll
    for (int n = 0; n < 8; ++n)
        #pragma unroll
        for (int i = 0; i < 4; ++i)
            C[(size_t)(rb + i) * H + n * 16 + fr] = acc[n][i];
}

// ---------------------------------------------------------------------------
// per-node attention scores: hs = h.a_src, hd = h.a_dst   (one wave per node)
// ---------------------------------------------------------------------------
__global__ void scores_k(const float* __restrict__ h, const float* __restrict__ a_s,
                         const float* __restrict__ a_d, float* __restrict__ hs,
                         float* __restrict__ hd, int n) {
    int wv = (blockIdx.x * blockDim.x + threadIdx.x) >> 6;
    int lane = threadIdx.x & 63;
    if (wv >= n) return;
    float v0 = h[(size_t)wv * H + lane];
    float v1 = h[(size_t)wv * H + 64 + lane];
    float s = v0 * a_s[lane] + v1 * a_s[64 + lane];
    float d = v0 * a_d[lane] + v1 * a_d[64 + lane];
    #pragma unroll
    for (int off = 32; off; off >>= 1) {
        s += __shfl_xor(s, off);
        d += __shfl_xor(d, off);
    }
    if (lane == 0) { hs[wv] = s; hd[wv] = d; }
}

// ---------------------------------------------------------------------------
// fused segment softmax + weighted aggregation, one wave per dst node.
// Fast path (deg<=64): single gather of indices+scores, in-wave max/sum
// reductions, then per-edge loop uses __shfl (no scalar gathers, no exp).
// ---------------------------------------------------------------------------
__global__ void attn_agg(const float* __restrict__ h, const float* __restrict__ hs,
                         const float* __restrict__ hd, const int* __restrict__ row_ptr,
                         const int* __restrict__ csr_src, const float* __restrict__ bias,
                         float* __restrict__ out, int n, int relu_flag) {
    int wv = (blockIdx.x * blockDim.x + threadIdx.x) >> 6;
    int lane = threadIdx.x & 63;
    if (wv >= n) return;
    int p0 = row_ptr[wv], p1 = row_ptr[wv + 1];
    int deg = p1 - p0;
    float hdi = hd[wv];
    float acc0 = 0.f, acc1 = 0.f;

    if (deg <= 64) {
        int valid = (lane < deg);
        int sidx = valid ? csr_src[p0 + lane] : 0;
        float e = hs[sidx] + hdi;
        e = (e >= 0.f) ? e : NEG_SLOPE * e;
        float ev = valid ? e : -3.4e38f;
        float m = ev;
        #pragma unroll
        for (int off = 32; off; off >>= 1) m = fmaxf(m, __shfl_xor(m, off));
        float pe = valid ? __expf(e - m) : 0.f;
        float dsum = pe;
        #pragma unroll
        for (int off = 32; off; off >>= 1) dsum += __shfl_xor(dsum, off);
        pe *= 1.f / (dsum + 1e-16f);
        for (int j = 0; j < deg; ++j) {
            float alpha = __shfl(pe, j);
            int s = __shfl(sidx, j);
            acc0 += alpha * h[(size_t)s * H + lane];
            acc1 += alpha * h[(size_t)s * H + 64 + lane];
        }
    } else {
        // general 3-pass path (verified round-1/2 code)
        float m = -3.4e38f;
        for (int p = p0 + lane; p < p1; p += 64) {
            float e = hs[csr_src[p]] + hdi;
            e = (e >= 0.f) ? e : NEG_SLOPE * e;
            m = fmaxf(m, e);
        }
        #pragma unroll
        for (int off = 32; off; off >>= 1) m = fmaxf(m, __shfl_xor(m, off));
        float dsum = 0.f;
        for (int p = p0 + lane; p < p1; p += 64) {
            float e = hs[csr_src[p]] + hdi;
            e = (e >= 0.f) ? e : NEG_SLOPE * e;
            dsum += __expf(e - m);
        }
        #pragma unroll
        for (int off = 32; off; off >>= 1) dsum += __shfl_xor(dsum, off);
        float inv = 1.f / (dsum + 1e-16f);
        for (int p = p0; p < p1; ++p) {
            int s = csr_src[p];
            float e = hs[s] + hdi;
            e = (e >= 0.f) ? e : NEG_SLOPE * e;
            float alpha = __expf(e - m) * inv;
            acc0 += alpha * h[(size_t)s * H + lane];
            acc1 += alpha * h[(size_t)s * H + 64 + lane];
        }
    }
    float o0 = acc0 + bias[lane];
    float o1 = acc1 + bias[64 + lane];
    if (relu_flag) { o0 = fmaxf(o0, 0.f); o1 = fmaxf(o1, 0.f); }
    out[(size_t)wv * H + lane] = o0;
    out[(size_t)wv * H + 64 + lane] = o1;
}

// ---------------------------------------------------------------------------
// global mean pool per graph (batch is sorted -> binary search boundaries)
// ---------------------------------------------------------------------------
__global__ void pool_k(const float* __restrict__ h, const int* __restrict__ batch,
                       float* __restrict__ pooled, int n) {
    int g = blockIdx.x;
    int f = threadIdx.x;
    int lo = 0, hi = n;
    while (lo < hi) { int mid = (lo + hi) >> 1; if (batch[mid] < g) lo = mid + 1; else hi = mid; }
    int start = lo;
    lo = start; hi = n;
    while (lo < hi) { int mid = (lo + hi) >> 1; if (batch[mid] < g + 1) lo = mid + 1; else hi = mid; }
    int end = lo;
    float acc = 0.f;
    for (int i = start; i < end; ++i) acc += h[(size_t)i * H + f];
    float cnt = (float)(end - start);
    pooled[g * H + f] = acc / fmaxf(cnt, 1.f);
}

// ---------------------------------------------------------------------------
// FC1 + BN(eval) + ReLU : z[64][1024]
// ---------------------------------------------------------------------------
__global__ void fc1_bn_relu(const float* __restrict__ pooled, const float* __restrict__ W,
                            const float* __restrict__ b, const float* __restrict__ bng,
                            const float* __restrict__ bnb, const float* __restrict__ bnrm,
                            const float* __restrict__ bnrv, float* __restrict__ z) {
    int g = blockIdx.x >> 2;
    int j = ((blockIdx.x & 3) << 8) + threadIdx.x;
    const float* pr = pooled + g * H;
    float acc = b[j];
    #pragma unroll 8
    for (int k = 0; k < H; ++k) acc += pr[k] * W[k * FC1D + j];
    float v = (acc - bnrm[j]) * rsqrtf(bnrv[j] + BN_EPS) * bng[j] + bnb[j];
    z[g * FC1D + j] = fmaxf(v, 0.f);
}

// ---------------------------------------------------------------------------
// FC2 + sigmoid : out[64][273]
// ---------------------------------------------------------------------------
__global__ void fc2_sig(const float* __restrict__ z, const float* __restrict__ W,
                        const float* __restrict__ b, float* __restrict__ out) {
    int g = blockIdx.x;
    int j = threadIdx.x;
    if (j >= OUTD) return;
    const float* zr = z + g * FC1D;
    float acc = b[j];
    #pragma unroll 4
    for (int k = 0; k < FC1D; ++k) acc += zr[k] * W[k * OUTD + j];
    out[g * OUTD + j] = 1.f / (1.f + __expf(-acc));
}

// ---------------------------------------------------------------------------
extern "C" void kernel_launch(void* const* d_in, const int* in_sizes, int n_in,
                              void* d_out, int out_size, void* d_ws, size_t ws_size,
                              hipStream_t stream) {
    const float* x     = (const float*)d_in[0];
    const int*   eidx  = (const int*)d_in[1];
    const int*   batch = (const int*)d_in[2];
    const float* W1 = (const float*)d_in[3];  const float* b1 = (const float*)d_in[4];
    const float* as1 = (const float*)d_in[5]; const float* ad1 = (const float*)d_in[6];
    const float* W2 = (const float*)d_in[7];  const float* b2 = (const float*)d_in[8];
    const float* as2 = (const float*)d_in[9]; const float* ad2 = (const float*)d_in[10];
    const float* W3 = (const float*)d_in[11]; const float* b3 = (const float*)d_in[12];
    const float* as3 = (const float*)d_in[13]; const float* ad3 = (const float*)d_in[14];
    const float* fc1W = (const float*)d_in[15]; const float* fc1b = (const float*)d_in[16];
    const float* bng = (const float*)d_in[17];  const float* bnb = (const float*)d_in[18];
    const float* bnrm = (const float*)d_in[19]; const float* bnrv = (const float*)d_in[20];
    const float* fc2W = (const float*)d_in[21]; const float* fc2b = (const float*)d_in[22];
    const int* src = eidx;
    const int* dst = eidx + N_EDGES;

    // workspace layout
    float* hW      = (float*)d_ws;                     // N*H
    float* hA      = hW + (size_t)N_NODES * H;         // N*H
    float* hs      = hA + (size_t)N_NODES * H;         // N
    float* hd      = hs + N_NODES;                     // N
    int*   row_ptr = (int*)(hd + N_NODES);             // N+1
    int*   row_cnt = row_ptr + (N_NODES + 1);          // N
    int*   csr_src = row_cnt + N_NODES;                // E
    float* pooled  = (float*)(csr_src + N_EDGES);      // G*H
    float* z       = pooled + NG * H;                  // G*1024
    unsigned short* wt1h = (unsigned short*)(z + NG * FC1D);   // 128*1280
    unsigned short* wt1l = wt1h + (size_t)H * F_IN;
    unsigned short* wt2h = wt1l + (size_t)H * F_IN;            // 128*128
    unsigned short* wt2l = wt2h + (size_t)H * H;
    unsigned short* wt3h = wt2l + (size_t)H * H;
    unsigned short* wt3l = wt3h + (size_t)H * H;

    const int EB = (N_EDGES + 255) / 256;
    const int NW = (N_NODES * 64 + 255) / 256;         // one wave per node
    const int GB = N_NODES / 64;                       // 625 gemm blocks

    // ---- weight split/transpose (tiny) ----
    wprep<<<(F_IN * H + 255) / 256, 256, 0, stream>>>(W1, wt1h, wt1l, F_IN);
    wprep<<<(H * H + 255) / 256, 256, 0, stream>>>(W2, wt2h, wt2l, H);
    wprep<<<(H * H + 255) / 256, 256, 0, stream>>>(W3, wt3h, wt3l, H);

    // ---- CSR build (by dst) ----
    hipMemsetAsync(row_cnt, 0, N_NODES * sizeof(int), stream);
    edge_hist<<<EB, 256, 0, stream>>>(dst, row_cnt, N_EDGES);
    scan_excl<<<1, 1024, 0, stream>>>(row_cnt, row_ptr, N_NODES);
    hipMemsetAsync(row_cnt, 0, N_NODES * sizeof(int), stream);
    edge_fill<<<EB, 256, 0, stream>>>(src, dst, row_ptr, row_cnt, csr_src, N_EDGES);

    // ---- layer 1 ----
    gemm_mfma<<<GB, 256, 0, stream>>>(x, wt1h, wt1l, hW, F_IN);
    scores_k<<<NW, 256, 0, stream>>>(hW, as1, ad1, hs, hd, N_NODES);
    attn_agg<<<NW, 256, 0, stream>>>(hW, hs, hd, row_ptr, csr_src, b1, hA, N_NODES, 1);
    // ---- layer 2 ----
    gemm_mfma<<<GB, 256, 0, stream>>>(hA, wt2h, wt2l, hW, H);
    scores_k<<<NW, 256, 0, stream>>>(hW, as2, ad2, hs, hd, N_NODES);
    attn_agg<<<NW, 256, 0, stream>>>(hW, hs, hd, row_ptr, csr_src, b2, hA, N_NODES, 1);
    // ---- layer 3 (no relu) ----
    gemm_mfma<<<GB, 256, 0, stream>>>(hA, wt3h, wt3l, hW, H);
    scores_k<<<NW, 256, 0, stream>>>(hW, as3, ad3, hs, hd, N_NODES);
    attn_agg<<<NW, 256, 0, stream>>>(hW, hs, hd, row_ptr, csr_src, b3, hA, N_NODES, 0);

    // ---- head ----
    pool_k<<<NG, H, 0, stream>>>(hA, batch, pooled, N_NODES);
    fc1_bn_relu<<<NG * 4, 256, 0, stream>>>(pooled, fc1W, fc1b, bng, bnb, bnrm, bnrv, z);
    fc2_sig<<<NG, 320, 0, stream>>>(z, fc2W, fc2b, (float*)d_out);
}

// Round 5
// 834.006 us; speedup vs baseline: 1.3778x; 1.3778x over previous
//
#include <hip/hip_runtime.h>
#include <math.h>

// Problem constants (from reference)
#define N_NODES 40000
#define N_EDGES 640000
#define F_IN    1280
#define H       128
#define NG      64
#define OUTD    273
#define FC1D    1024
#define NEG_SLOPE 0.2f
#define BN_EPS  1e-5f

typedef __attribute__((ext_vector_type(8))) short short8;
typedef __attribute__((ext_vector_type(4))) float f32x4;

// fp32 -> bf16 (RNE) and back, as bit patterns
__device__ __forceinline__ unsigned short f2bf(float f) {
    unsigned u = __float_as_uint(f);
    u += 0x7FFF + ((u >> 16) & 1);
    return (unsigned short)(u >> 16);
}
__device__ __forceinline__ float bf2f(unsigned short s) {
    return __uint_as_float((unsigned)s << 16);
}

// ---------------------------------------------------------------------------
// CSR build: histogram -> exclusive scan -> fill
// ---------------------------------------------------------------------------
__global__ void edge_hist(const int* __restrict__ dst, int* __restrict__ cnt, int e) {
    int i = blockIdx.x * blockDim.x + threadIdx.x;
    if (i < e) atomicAdd(&cnt[dst[i]], 1);
}

__global__ void scan_excl(const int* __restrict__ cnt, int* __restrict__ row_ptr, int n) {
    const int CH = 40;                      // 1024*40 = 40960 >= 40000
    __shared__ int sm[1024];
    int tid = threadIdx.x;
    int start = tid * CH;
    int local[CH];
    int s = 0;
    #pragma unroll
    for (int k = 0; k < CH; ++k) {
        int i = start + k;
        int v = (i < n) ? cnt[i] : 0;
        local[k] = s;
        s += v;
    }
    sm[tid] = s;
    __syncthreads();
    for (int off = 1; off < 1024; off <<= 1) {
        int t = (tid >= off) ? sm[tid - off] : 0;
        __syncthreads();
        sm[tid] += t;
        __syncthreads();
    }
    int base = sm[tid] - s;
    #pragma unroll
    for (int k = 0; k < CH; ++k) {
        int i = start + k;
        if (i < n) row_ptr[i] = base + local[k];
    }
    if (tid == 1023) row_ptr[n] = sm[1023];
}

__global__ void edge_fill(const int* __restrict__ src, const int* __restrict__ dst,
                          const int* __restrict__ row_ptr, int* __restrict__ fill,
                          int* __restrict__ csr_src, int e) {
    int i = blockIdx.x * blockDim.x + threadIdx.x;
    if (i < e) {
        int d = dst[i];
        int pos = row_ptr[d] + atomicAdd(&fill[d], 1);
        csr_src[pos] = src[i];
    }
}

// ---------------------------------------------------------------------------
// weight prep: W[K][128] fp32 -> Bp staged-chunk-linear bf16 hi/lo.
// Chunk t (64 k-values) = 16384 shorts: units U=0..2047, 8 shorts each.
//   hi unit: U = (n*2+s)*64 + lane, j=0..7 holds
//      hi(W[t*64 + s*32 + (lane>>4)*8 + j][n*16 + (lane&15)])
//   lo at U+1024.
// GEMM stages chunk t by a LINEAR 32 KB copy; LDS unit U at byte U*16 is
// exactly the MFMA B-fragment (n,s) for lane = U&63.
// ---------------------------------------------------------------------------
__global__ void wprep(const float* __restrict__ W, unsigned short* __restrict__ Bp, int K) {
    int i = blockIdx.x * blockDim.x + threadIdx.x;
    if (i >= K * H) return;
    int k = i >> 7, col = i & 127;
    float v = W[i];                        // W[k][col]
    unsigned short hh = f2bf(v);
    unsigned short ll = f2bf(v - bf2f(hh));
    int t = k >> 6, rr = k & 63;
    int s = rr >> 5, r5 = rr & 31;
    int laneHi = r5 >> 3, j = r5 & 7;
    int lane = laneHi * 16 + (col & 15);
    int n = col >> 4;
    int U = (n * 2 + s) * 64 + lane;
    size_t idx = (size_t)t * 16384 + (size_t)U * 8 + j;
    Bp[idx] = hh;
    Bp[idx + 8192] = ll;
}

// ---------------------------------------------------------------------------
// GEMM bf16x3 MFMA v3: C[M,128] = A[M,K] @ B[K,128]
//  - A: fp32 global -> regs -> hi/lo bf16 (no LDS)
//  - B: pre-staged Bp, linear 32 KB chunk copy via NAMED scalar regs
//    (no arrays -> no scratch spill; v2's 345 MB WRITE_SIZE was spill)
//  - 256 thr = 4 waves; wave = 16 rows x 128 cols; 48 MFMA per chunk
// ---------------------------------------------------------------------------
__device__ __forceinline__ void cvt8(float4 x, float4 y, short8& hi, short8& lo) {
    float f[8] = {x.x, x.y, x.z, x.w, y.x, y.y, y.z, y.w};
    #pragma unroll
    for (int j = 0; j < 8; ++j) {
        unsigned u = __float_as_uint(f[j]);
        unsigned short hh = (unsigned short)((u + 0x7FFF + ((u >> 16) & 1)) >> 16);
        hi[j] = (short)hh;
        float r = f[j] - __uint_as_float((unsigned)hh << 16);
        unsigned ur = __float_as_uint(r);
        lo[j] = (short)((ur + 0x7FFF + ((ur >> 16) & 1)) >> 16);
    }
}

__global__ __launch_bounds__(256) void gemm_mfma(
    const float* __restrict__ A, const unsigned short* __restrict__ Bp,
    float* __restrict__ C, int K)
{
    __shared__ __align__(16) unsigned short lds[16384];   // 32 KB = 1 chunk
    const int tid  = threadIdx.x;
    const int lane = tid & 63, wv = tid >> 6;
    const int fr = lane & 15, q = lane >> 4;
    const int m0 = blockIdx.x * 64;
    const int row = m0 + wv * 16 + fr;
    const int nt = K >> 6;

    const uint4* gb = (const uint4*)Bp + tid;
    uint4* lp = (uint4*)lds + tid;

    // prefetch chunk 0 (named regs only)
    uint4 f0 = gb[0],    f1 = gb[256],  f2 = gb[512],  f3 = gb[768],
          f4 = gb[1024], f5 = gb[1280], f6 = gb[1536], f7 = gb[1792];

    f32x4 acc0 = {}, acc1 = {}, acc2 = {}, acc3 = {},
          acc4 = {}, acc5 = {}, acc6 = {}, acc7 = {};

    for (int t = 0; t < nt; ++t) {
        lp[0] = f0;    lp[256] = f1;  lp[512] = f2;  lp[768] = f3;
        lp[1024] = f4; lp[1280] = f5; lp[1536] = f6; lp[1792] = f7;
        if (t + 1 < nt) {
            const uint4* g = gb + (size_t)(t + 1) * 2048;
            f0 = g[0];    f1 = g[256];  f2 = g[512];  f3 = g[768];
            f4 = g[1024]; f5 = g[1280]; f6 = g[1536]; f7 = g[1792];
        }
        __syncthreads();

        const float* ap = A + (size_t)row * K + t * 64 + q * 8;
        float4 a0 = *(const float4*)(ap);
        float4 a1 = *(const float4*)(ap + 4);
        float4 a2 = *(const float4*)(ap + 32);
        float4 a3 = *(const float4*)(ap + 36);

        short8 ah, al;
#define MSTEP(nn, accv, ss)                                                     \
        {                                                                       \
            const short8 bh = *(const short8*)&lds[(size_t)(((nn)*2+(ss))*64 + lane)*8];          \
            const short8 bl = *(const short8*)&lds[(size_t)(((nn)*2+(ss))*64 + lane)*8 + 8192];   \
            accv = __builtin_amdgcn_mfma_f32_16x16x32_bf16(ah, bh, accv, 0, 0, 0);                \
            accv = __builtin_amdgcn_mfma_f32_16x16x32_bf16(ah, bl, accv, 0, 0, 0);                \
            accv = __builtin_amdgcn_mfma_f32_16x16x32_bf16(al, bh, accv, 0, 0, 0);                \
        }
        cvt8(a0, a1, ah, al);
        MSTEP(0, acc0, 0) MSTEP(1, acc1, 0) MSTEP(2, acc2, 0) MSTEP(3, acc3, 0)
        MSTEP(4, acc4, 0) MSTEP(5, acc5, 0) MSTEP(6, acc6, 0) MSTEP(7, acc7, 0)
        cvt8(a2, a3, ah, al);
        MSTEP(0, acc0, 1) MSTEP(1, acc1, 1) MSTEP(2, acc2, 1) MSTEP(3, acc3, 1)
        MSTEP(4, acc4, 1) MSTEP(5, acc5, 1) MSTEP(6, acc6, 1) MSTEP(7, acc7, 1)
#undef MSTEP
        __syncthreads();
    }

    // epilogue: C/D layout col=lane&15, row=(lane>>4)*4+i  [m89]
    const int rb = m0 + wv * 16 + q * 4;
#define EPI(nn, accv)                                                           \
    {                                                                           \
        _Pragma("unroll")                                                       \
        for (int i = 0; i < 4; ++i)                                             \
            C[(size_t)(rb + i) * H + (nn)*16 + fr] = accv[i];                   \
    }
    EPI(0, acc0) EPI(1, acc1) EPI(2, acc2) EPI(3, acc3)
    EPI(4, acc4) EPI(5, acc5) EPI(6, acc6) EPI(7, acc7)
#undef EPI
}

// ---------------------------------------------------------------------------
// per-node attention scores: hs = h.a_src, hd = h.a_dst   (one wave per node)
// ---------------------------------------------------------------------------
__global__ void scores_k(const float* __restrict__ h, const float* __restrict__ a_s,
                         const float* __restrict__ a_d, float* __restrict__ hs,
                         float* __restrict__ hd, int n) {
    int wv = (blockIdx.x * blockDim.x + threadIdx.x) >> 6;
    int lane = threadIdx.x & 63;
    if (wv >= n) return;
    float v0 = h[(size_t)wv * H + lane];
    float v1 = h[(size_t)wv * H + 64 + lane];
    float s = v0 * a_s[lane] + v1 * a_s[64 + lane];
    float d = v0 * a_d[lane] + v1 * a_d[64 + lane];
    #pragma unroll
    for (int off = 32; off; off >>= 1) {
        s += __shfl_xor(s, off);
        d += __shfl_xor(d, off);
    }
    if (lane == 0) { hs[wv] = s; hd[wv] = d; }
}

// ---------------------------------------------------------------------------
// fused segment softmax + weighted aggregation, one wave per dst node.
// float2 gather: lane owns features {2*lane, 2*lane+1} -> one 512B wave load
// per edge instead of two 256B.
// ---------------------------------------------------------------------------
__global__ void attn_agg(const float* __restrict__ h, const float* __restrict__ hs,
                         const float* __restrict__ hd, const int* __restrict__ row_ptr,
                         const int* __restrict__ csr_src, const float* __restrict__ bias,
                         float* __restrict__ out, int n, int relu_flag) {
    int wv = (blockIdx.x * blockDim.x + threadIdx.x) >> 6;
    int lane = threadIdx.x & 63;
    if (wv >= n) return;
    int p0 = row_ptr[wv], p1 = row_ptr[wv + 1];
    int deg = p1 - p0;
    float hdi = hd[wv];
    float ax = 0.f, ay = 0.f;

    if (deg <= 64) {
        int valid = (lane < deg);
        int sidx = valid ? csr_src[p0 + lane] : 0;
        float e = hs[sidx] + hdi;
        e = (e >= 0.f) ? e : NEG_SLOPE * e;
        float ev = valid ? e : -3.4e38f;
        float m = ev;
        #pragma unroll
        for (int off = 32; off; off >>= 1) m = fmaxf(m, __shfl_xor(m, off));
        float pe = valid ? __expf(e - m) : 0.f;
        float dsum = pe;
        #pragma unroll
        for (int off = 32; off; off >>= 1) dsum += __shfl_xor(dsum, off);
        pe *= 1.f / (dsum + 1e-16f);
        for (int j = 0; j < deg; ++j) {
            float alpha = __shfl(pe, j);
            int s = __shfl(sidx, j);
            float2 hv = *(const float2*)&h[(size_t)s * H + 2 * lane];
            ax += alpha * hv.x;
            ay += alpha * hv.y;
        }
    } else {
        float m = -3.4e38f;
        for (int p = p0 + lane; p < p1; p += 64) {
            float e = hs[csr_src[p]] + hdi;
            e = (e >= 0.f) ? e : NEG_SLOPE * e;
            m = fmaxf(m, e);
        }
        #pragma unroll
        for (int off = 32; off; off >>= 1) m = fmaxf(m, __shfl_xor(m, off));
        float dsum = 0.f;
        for (int p = p0 + lane; p < p1; p += 64) {
            float e = hs[csr_src[p]] + hdi;
            e = (e >= 0.f) ? e : NEG_SLOPE * e;
            dsum += __expf(e - m);
        }
        #pragma unroll
        for (int off = 32; off; off >>= 1) dsum += __shfl_xor(dsum, off);
        float inv = 1.f / (dsum + 1e-16f);
        for (int p = p0; p < p1; ++p) {
            int s = csr_src[p];
            float e = hs[s] + hdi;
            e = (e >= 0.f) ? e : NEG_SLOPE * e;
            float alpha = __expf(e - m) * inv;
            float2 hv = *(const float2*)&h[(size_t)s * H + 2 * lane];
            ax += alpha * hv.x;
            ay += alpha * hv.y;
        }
    }
    float2 bv = *(const float2*)&bias[2 * lane];
    float o0 = ax + bv.x;
    float o1 = ay + bv.y;
    if (relu_flag) { o0 = fmaxf(o0, 0.f); o1 = fmaxf(o1, 0.f); }
    float2 ov; ov.x = o0; ov.y = o1;
    *(float2*)&out[(size_t)wv * H + 2 * lane] = ov;
}

// ---------------------------------------------------------------------------
// global mean pool per graph, two-stage (batch sorted -> binary search)
// ---------------------------------------------------------------------------
__device__ __forceinline__ void graph_range(const int* __restrict__ batch, int n,
                                            int g, int& start, int& end) {
    int lo = 0, hi = n;
    while (lo < hi) { int mid = (lo + hi) >> 1; if (batch[mid] < g) lo = mid + 1; else hi = mid; }
    start = lo;
    lo = start; hi = n;
    while (lo < hi) { int mid = (lo + hi) >> 1; if (batch[mid] < g + 1) lo = mid + 1; else hi = mid; }
    end = lo;
}

__global__ void pool_part(const float* __restrict__ h, const int* __restrict__ batch,
                          float* __restrict__ part, int n) {
    int g = blockIdx.x >> 3, c = blockIdx.x & 7;
    int f = threadIdx.x;                     // 128
    int start, end;
    graph_range(batch, n, g, start, end);
    int len = end - start;
    int cs = start + (len * c) / 8, ce = start + (len * (c + 1)) / 8;
    float acc = 0.f;
    for (int i = cs; i < ce; ++i) acc += h[(size_t)i * H + f];
    part[((size_t)g * 8 + c) * H + f] = acc;
}

__global__ void pool_final(const float* __restrict__ part, const int* __restrict__ batch,
                           float* __restrict__ pooled, int n) {
    int g = blockIdx.x;
    int f = threadIdx.x;
    int start, end;
    graph_range(batch, n, g, start, end);
    float s = 0.f;
    #pragma unroll
    for (int c = 0; c < 8; ++c) s += part[((size_t)g * 8 + c) * H + f];
    float cnt = (float)(end - start);
    pooled[g * H + f] = s / fmaxf(cnt, 1.f);
}

// ---------------------------------------------------------------------------
// FC1 + BN(eval) + ReLU : z[64][1024]
// ---------------------------------------------------------------------------
__global__ void fc1_bn_relu(const float* __restrict__ pooled, const float* __restrict__ W,
                            const float* __restrict__ b, const float* __restrict__ bng,
                            const float* __restrict__ bnb, const float* __restrict__ bnrm,
                            const float* __restrict__ bnrv, float* __restrict__ z) {
    int g = blockIdx.x >> 2;
    int j = ((blockIdx.x & 3) << 8) + threadIdx.x;
    const float* pr = pooled + g * H;
    float acc = b[j];
    #pragma unroll 8
    for (int k = 0; k < H; ++k) acc += pr[k] * W[k * FC1D + j];
    float v = (acc - bnrm[j]) * rsqrtf(bnrv[j] + BN_EPS) * bng[j] + bnb[j];
    z[g * FC1D + j] = fmaxf(v, 0.f);
}

// ---------------------------------------------------------------------------
// FC2 + sigmoid : out[64][273]
// ---------------------------------------------------------------------------
__global__ void fc2_sig(const float* __restrict__ z, const float* __restrict__ W,
                        const float* __restrict__ b, float* __restrict__ out) {
    int g = blockIdx.x;
    int j = threadIdx.x;
    if (j >= OUTD) return;
    const float* zr = z + g * FC1D;
    float acc = b[j];
    #pragma unroll 4
    for (int k = 0; k < FC1D; ++k) acc += zr[k] * W[k * OUTD + j];
    out[g * OUTD + j] = 1.f / (1.f + __expf(-acc));
}

// ---------------------------------------------------------------------------
extern "C" void kernel_launch(void* const* d_in, const int* in_sizes, int n_in,
                              void* d_out, int out_size, void* d_ws, size_t ws_size,
                              hipStream_t stream) {
    const float* x     = (const float*)d_in[0];
    const int*   eidx  = (const int*)d_in[1];
    const int*   batch = (const int*)d_in[2];
    const float* W1 = (const float*)d_in[3];  const float* b1 = (const float*)d_in[4];
    const float* as1 = (const float*)d_in[5]; const float* ad1 = (const float*)d_in[6];
    const float* W2 = (const float*)d_in[7];  const float* b2 = (const float*)d_in[8];
    const float* as2 = (const float*)d_in[9]; const float* ad2 = (const float*)d_in[10];
    const float* W3 = (const float*)d_in[11]; const float* b3 = (const float*)d_in[12];
    const float* as3 = (const float*)d_in[13]; const float* ad3 = (const float*)d_in[14];
    const float* fc1W = (const float*)d_in[15]; const float* fc1b = (const float*)d_in[16];
    const float* bng = (const float*)d_in[17];  const float* bnb = (const float*)d_in[18];
    const float* bnrm = (const float*)d_in[19]; const float* bnrv = (const float*)d_in[20];
    const float* fc2W = (const float*)d_in[21]; const float* fc2b = (const float*)d_in[22];
    const int* src = eidx;
    const int* dst = eidx + N_EDGES;

    // workspace layout
    float* hW      = (float*)d_ws;                     // N*H
    float* hA      = hW + (size_t)N_NODES * H;         // N*H
    float* hs      = hA + (size_t)N_NODES * H;         // N
    float* hd      = hs + N_NODES;                     // N
    int*   row_ptr = (int*)(hd + N_NODES);             // N+1
    int*   row_cnt = row_ptr + (N_NODES + 1);          // N
    int*   csr_src = row_cnt + N_NODES;                // E
    float* pooled  = (float*)(csr_src + N_EDGES);      // G*H
    float* part    = pooled + NG * H;                  // G*8*H
    float* z       = part + NG * 8 * H;                // G*1024
    unsigned short* Bp1 = (unsigned short*)(z + NG * FC1D);    // 20 chunks * 16384
    unsigned short* Bp2 = Bp1 + (size_t)(F_IN / 64) * 16384;   // 2 chunks
    unsigned short* Bp3 = Bp2 + (size_t)(H / 64) * 16384;      // 2 chunks

    const int EB = (N_EDGES + 255) / 256;
    const int NW = (N_NODES * 64 + 255) / 256;         // one wave per node
    const int GB = N_NODES / 64;                       // 625 gemm blocks

    // ---- weight prep into staged order (tiny) ----
    wprep<<<(F_IN * H + 255) / 256, 256, 0, stream>>>(W1, Bp1, F_IN);
    wprep<<<(H * H + 255) / 256, 256, 0, stream>>>(W2, Bp2, H);
    wprep<<<(H * H + 255) / 256, 256, 0, stream>>>(W3, Bp3, H);

    // ---- CSR build (by dst) ----
    hipMemsetAsync(row_cnt, 0, N_NODES * sizeof(int), stream);
    edge_hist<<<EB, 256, 0, stream>>>(dst, row_cnt, N_EDGES);
    scan_excl<<<1, 1024, 0, stream>>>(row_cnt, row_ptr, N_NODES);
    hipMemsetAsync(row_cnt, 0, N_NODES * sizeof(int), stream);
    edge_fill<<<EB, 256, 0, stream>>>(src, dst, row_ptr, row_cnt, csr_src, N_EDGES);

    // ---- layer 1 ----
    gemm_mfma<<<GB, 256, 0, stream>>>(x, Bp1, hW, F_IN);
    scores_k<<<NW, 256, 0, stream>>>(hW, as1, ad1, hs, hd, N_NODES);
    attn_agg<<<NW, 256, 0, stream>>>(hW, hs, hd, row_ptr, csr_src, b1, hA, N_NODES, 1);
    // ---- layer 2 ----
    gemm_mfma<<<GB, 256, 0, stream>>>(hA, Bp2, hW, H);
    scores_k<<<NW, 256, 0, stream>>>(hW, as2, ad2, hs, hd, N_NODES);
    attn_agg<<<NW, 256, 0, stream>>>(hW, hs, hd, row_ptr, csr_src, b2, hA, N_NODES, 1);
    // ---- layer 3 (no relu) ----
    gemm_mfma<<<GB, 256, 0, stream>>>(hA, Bp3, hW, H);
    scores_k<<<NW, 256, 0, stream>>>(hW, as3, ad3, hs, hd, N_NODES);
    attn_agg<<<NW, 256, 0, stream>>>(hW, hs, hd, row_ptr, csr_src, b3, hA, N_NODES, 0);

    // ---- head ----
    pool_part<<<NG * 8, H, 0, stream>>>(hA, batch, part, N_NODES);
    pool_final<<<NG, H, 0, stream>>>(part, batch, pooled, N_NODES);
    fc1_bn_relu<<<NG * 4, 256, 0, stream>>>(pooled, fc1W, fc1b, bng, bnb, bnrm, bnrv, z);
    fc2_sig<<<NG, 320, 0, stream>>>(z, fc2W, fc2b, (float*)d_out);
}

// Round 6
// 744.888 us; speedup vs baseline: 1.5427x; 1.1196x over previous
//
#include <hip/hip_runtime.h>
#include <math.h>

// Problem constants (from reference)
#define N_NODES 40000
#define N_EDGES 640000
#define F_IN    1280
#define H       128
#define NG      64
#define OUTD    273
#define FC1D    1024
#define NEG_SLOPE 0.2f
#define BN_EPS  1e-5f

typedef __attribute__((ext_vector_type(8))) short short8;
typedef __attribute__((ext_vector_type(4))) float f32x4;

// fp32 -> bf16 (RNE) and back, as bit patterns
__device__ __forceinline__ unsigned short f2bf(float f) {
    unsigned u = __float_as_uint(f);
    u += 0x7FFF + ((u >> 16) & 1);
    return (unsigned short)(u >> 16);
}
__device__ __forceinline__ float bf2f(unsigned short s) {
    return __uint_as_float((unsigned)s << 16);
}

// ---------------------------------------------------------------------------
// CSR build: histogram -> exclusive scan -> fill
// ---------------------------------------------------------------------------
__global__ void edge_hist(const int* __restrict__ dst, int* __restrict__ cnt, int e) {
    int i = blockIdx.x * blockDim.x + threadIdx.x;
    if (i < e) atomicAdd(&cnt[dst[i]], 1);
}

__global__ void scan_excl(const int* __restrict__ cnt, int* __restrict__ row_ptr, int n) {
    const int CH = 40;                      // 1024*40 = 40960 >= 40000
    __shared__ int sm[1024];
    int tid = threadIdx.x;
    int start = tid * CH;
    int local[CH];
    int s = 0;
    #pragma unroll
    for (int k = 0; k < CH; ++k) {
        int i = start + k;
        int v = (i < n) ? cnt[i] : 0;
        local[k] = s;
        s += v;
    }
    sm[tid] = s;
    __syncthreads();
    for (int off = 1; off < 1024; off <<= 1) {
        int t = (tid >= off) ? sm[tid - off] : 0;
        __syncthreads();
        sm[tid] += t;
        __syncthreads();
    }
    int base = sm[tid] - s;
    #pragma unroll
    for (int k = 0; k < CH; ++k) {
        int i = start + k;
        if (i < n) row_ptr[i] = base + local[k];
    }
    if (tid == 1023) row_ptr[n] = sm[1023];
}

__global__ void edge_fill(const int* __restrict__ src, const int* __restrict__ dst,
                          const int* __restrict__ row_ptr, int* __restrict__ fill,
                          int* __restrict__ csr_src, int e) {
    int i = blockIdx.x * blockDim.x + threadIdx.x;
    if (i < e) {
        int d = dst[i];
        int pos = row_ptr[d] + atomicAdd(&fill[d], 1);
        csr_src[pos] = src[i];
    }
}

// ---------------------------------------------------------------------------
// weight prep: W[K][128] fp32 -> Bp staged-chunk-linear bf16 hi/lo.
// Chunk t (64 k) = 16384 shorts; unit U=(n*2+s)*64+lane holds 8 shorts:
//   hi(W[t*64 + s*32 + (lane>>4)*8 + j][n*16 + (lane&15)]),  lo at +8192.
// GEMM stages a chunk with a LINEAR 32 KB copy.
// ---------------------------------------------------------------------------
__global__ void wprep(const float* __restrict__ W, unsigned short* __restrict__ Bp, int K) {
    int i = blockIdx.x * blockDim.x + threadIdx.x;
    if (i >= K * H) return;
    int k = i >> 7, col = i & 127;
    float v = W[i];                        // W[k][col]
    unsigned short hh = f2bf(v);
    unsigned short ll = f2bf(v - bf2f(hh));
    int t = k >> 6, rr = k & 63;
    int s = rr >> 5, r5 = rr & 31;
    int laneHi = r5 >> 3, j = r5 & 7;
    int lane = laneHi * 16 + (col & 15);
    int n = col >> 4;
    int U = (n * 2 + s) * 64 + lane;
    size_t idx = (size_t)t * 16384 + (size_t)U * 8 + j;
    Bp[idx] = hh;
    Bp[idx + 8192] = ll;
}

// ---------------------------------------------------------------------------
// GEMM bf16x3 MFMA v4: h = A @ W with FUSED per-row attention scores.
//  - writes hW as bf16 (gather target), hs = h.a_src, hd = h.a_dst in fp32
//    (computed from fp32 accumulators BEFORE bf16 rounding)
//  - A: fp32 global -> regs -> hi/lo bf16 (no LDS); B: pre-staged Bp, linear
//    32 KB chunk copy via NAMED regs (no arrays -> no scratch spill)
// ---------------------------------------------------------------------------
__device__ __forceinline__ void cvt8(float4 x, float4 y, short8& hi, short8& lo) {
    float f[8] = {x.x, x.y, x.z, x.w, y.x, y.y, y.z, y.w};
    #pragma unroll
    for (int j = 0; j < 8; ++j) {
        unsigned u = __float_as_uint(f[j]);
        unsigned short hh = (unsigned short)((u + 0x7FFF + ((u >> 16) & 1)) >> 16);
        hi[j] = (short)hh;
        float r = f[j] - __uint_as_float((unsigned)hh << 16);
        unsigned ur = __float_as_uint(r);
        lo[j] = (short)((ur + 0x7FFF + ((ur >> 16) & 1)) >> 16);
    }
}

__global__ __launch_bounds__(256) void gemm_fused(
    const float* __restrict__ A, const unsigned short* __restrict__ Bp,
    const float* __restrict__ a_src, const float* __restrict__ a_dst,
    unsigned short* __restrict__ hWb, float* __restrict__ hs,
    float* __restrict__ hd, int K)
{
    __shared__ __align__(16) unsigned short lds[16384];   // 32 KB = 1 chunk
    const int tid  = threadIdx.x;
    const int lane = tid & 63, wv = tid >> 6;
    const int fr = lane & 15, q = lane >> 4;
    const int m0 = blockIdx.x * 64;
    const int row = m0 + wv * 16 + fr;
    const int nt = K >> 6;

    const uint4* gb = (const uint4*)Bp + tid;
    uint4* lp = (uint4*)lds + tid;

    // prefetch chunk 0 (named regs only)
    uint4 f0 = gb[0],    f1 = gb[256],  f2 = gb[512],  f3 = gb[768],
          f4 = gb[1024], f5 = gb[1280], f6 = gb[1536], f7 = gb[1792];

    f32x4 acc0 = {}, acc1 = {}, acc2 = {}, acc3 = {},
          acc4 = {}, acc5 = {}, acc6 = {}, acc7 = {};

    for (int t = 0; t < nt; ++t) {
        lp[0] = f0;    lp[256] = f1;  lp[512] = f2;  lp[768] = f3;
        lp[1024] = f4; lp[1280] = f5; lp[1536] = f6; lp[1792] = f7;
        if (t + 1 < nt) {
            const uint4* g = gb + (size_t)(t + 1) * 2048;
            f0 = g[0];    f1 = g[256];  f2 = g[512];  f3 = g[768];
            f4 = g[1024]; f5 = g[1280]; f6 = g[1536]; f7 = g[1792];
        }
        __syncthreads();

        const float* ap = A + (size_t)row * K + t * 64 + q * 8;
        float4 a0 = *(const float4*)(ap);
        float4 a1 = *(const float4*)(ap + 4);
        float4 a2 = *(const float4*)(ap + 32);
        float4 a3 = *(const float4*)(ap + 36);

        short8 ah, al;
#define MSTEP(nn, accv, ss)                                                     \
        {                                                                       \
            const short8 bh = *(const short8*)&lds[(size_t)(((nn)*2+(ss))*64 + lane)*8];          \
            const short8 bl = *(const short8*)&lds[(size_t)(((nn)*2+(ss))*64 + lane)*8 + 8192];   \
            accv = __builtin_amdgcn_mfma_f32_16x16x32_bf16(ah, bh, accv, 0, 0, 0);                \
            accv = __builtin_amdgcn_mfma_f32_16x16x32_bf16(ah, bl, accv, 0, 0, 0);                \
            accv = __builtin_amdgcn_mfma_f32_16x16x32_bf16(al, bh, accv, 0, 0, 0);                \
        }
        cvt8(a0, a1, ah, al);
        MSTEP(0, acc0, 0) MSTEP(1, acc1, 0) MSTEP(2, acc2, 0) MSTEP(3, acc3, 0)
        MSTEP(4, acc4, 0) MSTEP(5, acc5, 0) MSTEP(6, acc6, 0) MSTEP(7, acc7, 0)
        cvt8(a2, a3, ah, al);
        MSTEP(0, acc0, 1) MSTEP(1, acc1, 1) MSTEP(2, acc2, 1) MSTEP(3, acc3, 1)
        MSTEP(4, acc4, 1) MSTEP(5, acc5, 1) MSTEP(6, acc6, 1) MSTEP(7, acc7, 1)
#undef MSTEP
        __syncthreads();
    }

    // ---- epilogue 1: bf16 h store. C/D layout col=lane&15, row=(lane>>4)*4+i
    const int rb = m0 + wv * 16 + q * 4;
#define EPI(nn, accv)                                                           \
    {                                                                           \
        _Pragma("unroll")                                                       \
        for (int i = 0; i < 4; ++i)                                             \
            hWb[(size_t)(rb + i) * H + (nn)*16 + fr] = f2bf(accv[i]);           \
    }
    EPI(0, acc0) EPI(1, acc1) EPI(2, acc2) EPI(3, acc3)
    EPI(4, acc4) EPI(5, acc5) EPI(6, acc6) EPI(7, acc7)
#undef EPI

    // ---- epilogue 2: fused scores hs/hd from fp32 acc ----
    float asv[8], adv[8];
    #pragma unroll
    for (int n = 0; n < 8; ++n) {
        asv[n] = a_src[n * 16 + fr];
        adv[n] = a_dst[n * 16 + fr];
    }
    #pragma unroll
    for (int i = 0; i < 4; ++i) {
        float ss = acc0[i]*asv[0] + acc1[i]*asv[1] + acc2[i]*asv[2] + acc3[i]*asv[3]
                 + acc4[i]*asv[4] + acc5[i]*asv[5] + acc6[i]*asv[6] + acc7[i]*asv[7];
        float dd = acc0[i]*adv[0] + acc1[i]*adv[1] + acc2[i]*adv[2] + acc3[i]*adv[3]
                 + acc4[i]*adv[4] + acc5[i]*adv[5] + acc6[i]*adv[6] + acc7[i]*adv[7];
        #pragma unroll
        for (int off = 8; off; off >>= 1) {
            ss += __shfl_xor(ss, off);
            dd += __shfl_xor(dd, off);
        }
        if (fr == 0) { hs[rb + i] = ss; hd[rb + i] = dd; }
    }
}

// ---------------------------------------------------------------------------
// fused segment softmax + weighted aggregation, one wave per dst node.
// h gathered as bf16 pairs (256 B/edge/wave); per-edge loop unrolled x4 for
// memory-level parallelism. Output fp32 (+bias, optional relu).
// ---------------------------------------------------------------------------
__device__ __forceinline__ float bfhi(unsigned u) { return __uint_as_float(u << 16); }
__device__ __forceinline__ float bflo(unsigned u) { return __uint_as_float(u & 0xffff0000u); }

__global__ void attn_agg(const unsigned short* __restrict__ hWb,
                         const float* __restrict__ hs, const float* __restrict__ hd,
                         const int* __restrict__ row_ptr, const int* __restrict__ csr_src,
                         const float* __restrict__ bias, float* __restrict__ out,
                         int n, int relu_flag) {
    int wv = (blockIdx.x * blockDim.x + threadIdx.x) >> 6;
    int lane = threadIdx.x & 63;
    if (wv >= n) return;
    int p0 = row_ptr[wv], p1 = row_ptr[wv + 1];
    int deg = p1 - p0;
    float hdi = hd[wv];
    float ax = 0.f, ay = 0.f;
    const unsigned* hb = (const unsigned*)hWb;     // 64 bf16-pairs per row

    if (deg <= 64) {
        int valid = (lane < deg);
        int sidx = valid ? csr_src[p0 + lane] : 0;
        float e = hs[sidx] + hdi;
        e = (e >= 0.f) ? e : NEG_SLOPE * e;
        float ev = valid ? e : -3.4e38f;
        float m = ev;
        #pragma unroll
        for (int off = 32; off; off >>= 1) m = fmaxf(m, __shfl_xor(m, off));
        float pe = valid ? __expf(e - m) : 0.f;
        float dsum = pe;
        #pragma unroll
        for (int off = 32; off; off >>= 1) dsum += __shfl_xor(dsum, off);
        pe *= 1.f / (dsum + 1e-16f);

        int j = 0;
        int dq = deg & ~3;
        for (; j < dq; j += 4) {
            float al0 = __shfl(pe, j),     al1 = __shfl(pe, j + 1);
            float al2 = __shfl(pe, j + 2), al3 = __shfl(pe, j + 3);
            int s0 = __shfl(sidx, j),     s1 = __shfl(sidx, j + 1);
            int s2 = __shfl(sidx, j + 2), s3 = __shfl(sidx, j + 3);
            unsigned u0 = hb[(size_t)s0 * 64 + lane];
            unsigned u1 = hb[(size_t)s1 * 64 + lane];
            unsigned u2 = hb[(size_t)s2 * 64 + lane];
            unsigned u3 = hb[(size_t)s3 * 64 + lane];
            ax += al0 * bfhi(u0); ay += al0 * bflo(u0);
            ax += al1 * bfhi(u1); ay += al1 * bflo(u1);
            ax += al2 * bfhi(u2); ay += al2 * bflo(u2);
            ax += al3 * bfhi(u3); ay += al3 * bflo(u3);
        }
        for (; j < deg; ++j) {
            float alpha = __shfl(pe, j);
            int s = __shfl(sidx, j);
            unsigned u = hb[(size_t)s * 64 + lane];
            ax += alpha * bfhi(u); ay += alpha * bflo(u);
        }
    } else {
        float m = -3.4e38f;
        for (int p = p0 + lane; p < p1; p += 64) {
            float e = hs[csr_src[p]] + hdi;
            e = (e >= 0.f) ? e : NEG_SLOPE * e;
            m = fmaxf(m, e);
        }
        #pragma unroll
        for (int off = 32; off; off >>= 1) m = fmaxf(m, __shfl_xor(m, off));
        float dsum = 0.f;
        for (int p = p0 + lane; p < p1; p += 64) {
            float e = hs[csr_src[p]] + hdi;
            e = (e >= 0.f) ? e : NEG_SLOPE * e;
            dsum += __expf(e - m);
        }
        #pragma unroll
        for (int off = 32; off; off >>= 1) dsum += __shfl_xor(dsum, off);
        float inv = 1.f / (dsum + 1e-16f);
        for (int p = p0; p < p1; ++p) {
            int s = csr_src[p];
            float e = hs[s] + hdi;
            e = (e >= 0.f) ? e : NEG_SLOPE * e;
            float alpha = __expf(e - m) * inv;
            unsigned u = hb[(size_t)s * 64 + lane];
            ax += alpha * bfhi(u); ay += alpha * bflo(u);
        }
    }
    float2 bv = *(const float2*)&bias[2 * lane];
    float o0 = ax + bv.x;
    float o1 = ay + bv.y;
    if (relu_flag) { o0 = fmaxf(o0, 0.f); o1 = fmaxf(o1, 0.f); }
    float2 ov; ov.x = o0; ov.y = o1;
    *(float2*)&out[(size_t)wv * H + 2 * lane] = ov;
}

// ---------------------------------------------------------------------------
// global mean pool per graph, two-stage (batch sorted -> binary search)
// ---------------------------------------------------------------------------
__device__ __forceinline__ void graph_range(const int* __restrict__ batch, int n,
                                            int g, int& start, int& end) {
    int lo = 0, hi = n;
    while (lo < hi) { int mid = (lo + hi) >> 1; if (batch[mid] < g) lo = mid + 1; else hi = mid; }
    start = lo;
    lo = start; hi = n;
    while (lo < hi) { int mid = (lo + hi) >> 1; if (batch[mid] < g + 1) lo = mid + 1; else hi = mid; }
    end = lo;
}

__global__ void pool_part(const float* __restrict__ h, const int* __restrict__ batch,
                          float* __restrict__ part, int n) {
    int g = blockIdx.x >> 3, c = blockIdx.x & 7;
    int f = threadIdx.x;                     // 128
    int start, end;
    graph_range(batch, n, g, start, end);
    int len = end - start;
    int cs = start + (len * c) / 8, ce = start + (len * (c + 1)) / 8;
    float acc = 0.f;
    for (int i = cs; i < ce; ++i) acc += h[(size_t)i * H + f];
    part[((size_t)g * 8 + c) * H + f] = acc;
}

__global__ void pool_final(const float* __restrict__ part, const int* __restrict__ batch,
                           float* __restrict__ pooled, int n) {
    int g = blockIdx.x;
    int f = threadIdx.x;
    int start, end;
    graph_range(batch, n, g, start, end);
    float s = 0.f;
    #pragma unroll
    for (int c = 0; c < 8; ++c) s += part[((size_t)g * 8 + c) * H + f];
    float cnt = (float)(end - start);
    pooled[g * H + f] = s / fmaxf(cnt, 1.f);
}

// ---------------------------------------------------------------------------
// FC1 + BN(eval) + ReLU : z[64][1024]
// ---------------------------------------------------------------------------
__global__ void fc1_bn_relu(const float* __restrict__ pooled, const float* __restrict__ W,
                            const float* __restrict__ b, const float* __restrict__ bng,
                            const float* __restrict__ bnb, const float* __restrict__ bnrm,
                            const float* __restrict__ bnrv, float* __restrict__ z) {
    int g = blockIdx.x >> 2;
    int j = ((blockIdx.x & 3) << 8) + threadIdx.x;
    const float* pr = pooled + g * H;
    float acc = b[j];
    #pragma unroll 8
    for (int k = 0; k < H; ++k) acc += pr[k] * W[k * FC1D + j];
    float v = (acc - bnrm[j]) * rsqrtf(bnrv[j] + BN_EPS) * bng[j] + bnb[j];
    z[g * FC1D + j] = fmaxf(v, 0.f);
}

// ---------------------------------------------------------------------------
// FC2 + sigmoid : out[64][273]
// ---------------------------------------------------------------------------
__global__ void fc2_sig(const float* __restrict__ z, const float* __restrict__ W,
                        const float* __restrict__ b, float* __restrict__ out) {
    int g = blockIdx.x;
    int j = threadIdx.x;
    if (j >= OUTD) return;
    const float* zr = z + g * FC1D;
    float acc = b[j];
    #pragma unroll 4
    for (int k = 0; k < FC1D; ++k) acc += zr[k] * W[k * OUTD + j];
    out[g * OUTD + j] = 1.f / (1.f + __expf(-acc));
}

// ---------------------------------------------------------------------------
extern "C" void kernel_launch(void* const* d_in, const int* in_sizes, int n_in,
                              void* d_out, int out_size, void* d_ws, size_t ws_size,
                              hipStream_t stream) {
    const float* x     = (const float*)d_in[0];
    const int*   eidx  = (const int*)d_in[1];
    const int*   batch = (const int*)d_in[2];
    const float* W1 = (const float*)d_in[3];  const float* b1 = (const float*)d_in[4];
    const float* as1 = (const float*)d_in[5]; const float* ad1 = (const float*)d_in[6];
    const float* W2 = (const float*)d_in[7];  const float* b2 = (const float*)d_in[8];
    const float* as2 = (const float*)d_in[9]; const float* ad2 = (const float*)d_in[10];
    const float* W3 = (const float*)d_in[11]; const float* b3 = (const float*)d_in[12];
    const float* as3 = (const float*)d_in[13]; const float* ad3 = (const float*)d_in[14];
    const float* fc1W = (const float*)d_in[15]; const float* fc1b = (const float*)d_in[16];
    const float* bng = (const float*)d_in[17];  const float* bnb = (const float*)d_in[18];
    const float* bnrm = (const float*)d_in[19]; const float* bnrv = (const float*)d_in[20];
    const float* fc2W = (const float*)d_in[21]; const float* fc2b = (const float*)d_in[22];
    const int* src = eidx;
    const int* dst = eidx + N_EDGES;

    // workspace layout (fp32 region, then bf16/short region, then int region)
    float* hA      = (float*)d_ws;                     // N*H fp32 (attn out / gemm A)
    float* hs      = hA + (size_t)N_NODES * H;         // N
    float* hd      = hs + N_NODES;                     // N
    float* pooled  = hd + N_NODES;                     // G*H
    float* part    = pooled + NG * H;                  // G*8*H
    float* z       = part + NG * 8 * H;                // G*1024
    unsigned short* hWb = (unsigned short*)(z + NG * FC1D);    // N*H bf16
    unsigned short* Bp1 = hWb + (size_t)N_NODES * H;           // 20 chunks * 16384
    unsigned short* Bp2 = Bp1 + (size_t)(F_IN / 64) * 16384;   // 2 chunks
    unsigned short* Bp3 = Bp2 + (size_t)(H / 64) * 16384;      // 2 chunks
    int*   row_ptr = (int*)(Bp3 + (size_t)(H / 64) * 16384);   // N+1
    int*   row_cnt = row_ptr + (N_NODES + 1);          // N
    int*   csr_src = row_cnt + N_NODES;                // E

    const int EB = (N_EDGES + 255) / 256;
    const int NW = (N_NODES * 64 + 255) / 256;         // one wave per node
    const int GB = N_NODES / 64;                       // 625 gemm blocks

    // ---- weight prep into staged order (tiny) ----
    wprep<<<(F_IN * H + 255) / 256, 256, 0, stream>>>(W1, Bp1, F_IN);
    wprep<<<(H * H + 255) / 256, 256, 0, stream>>>(W2, Bp2, H);
    wprep<<<(H * H + 255) / 256, 256, 0, stream>>>(W3, Bp3, H);

    // ---- CSR build (by dst) ----
    hipMemsetAsync(row_cnt, 0, N_NODES * sizeof(int), stream);
    edge_hist<<<EB, 256, 0, stream>>>(dst, row_cnt, N_EDGES);
    scan_excl<<<1, 1024, 0, stream>>>(row_cnt, row_ptr, N_NODES);
    hipMemsetAsync(row_cnt, 0, N_NODES * sizeof(int), stream);
    edge_fill<<<EB, 256, 0, stream>>>(src, dst, row_ptr, row_cnt, csr_src, N_EDGES);

    // ---- layer 1 ----
    gemm_fused<<<GB, 256, 0, stream>>>(x, Bp1, as1, ad1, hWb, hs, hd, F_IN);
    attn_agg<<<NW, 256, 0, stream>>>(hWb, hs, hd, row_ptr, csr_src, b1, hA, N_NODES, 1);
    // ---- layer 2 ----
    gemm_fused<<<GB, 256, 0, stream>>>(hA, Bp2, as2, ad2, hWb, hs, hd, H);
    attn_agg<<<NW, 256, 0, stream>>>(hWb, hs, hd, row_ptr, csr_src, b2, hA, N_NODES, 1);
    // ---- layer 3 (no relu) ----
    gemm_fused<<<GB, 256, 0, stream>>>(hA, Bp3, as3, ad3, hWb, hs, hd, H);
    attn_agg<<<NW, 256, 0, stream>>>(hWb, hs, hd, row_ptr, csr_src, b3, hA, N_NODES, 0);

    // ---- head ----
    pool_part<<<NG * 8, H, 0, stream>>>(hA, batch, part, N_NODES);
    pool_final<<<NG, H, 0, stream>>>(part, batch, pooled, N_NODES);
    fc1_bn_relu<<<NG * 4, 256, 0, stream>>>(pooled, fc1W, fc1b, bng, bnb, bnrm, bnrv, z);
    fc2_sig<<<NG, 320, 0, stream>>>(z, fc2W, fc2b, (float*)d_out);
}

// Round 7
// 742.756 us; speedup vs baseline: 1.5471x; 1.0029x over previous
//
#include <hip/hip_runtime.h>
#include <math.h>

// Problem constants (from reference)
#define N_NODES 40000
#define N_EDGES 640000
#define F_IN    1280
#define H       128
#define NG      64
#define OUTD    273
#define FC1D    1024
#define NEG_SLOPE 0.2f
#define BN_EPS  1e-5f

typedef __attribute__((ext_vector_type(8))) short short8;
typedef __attribute__((ext_vector_type(4))) float f32x4;

__device__ __forceinline__ unsigned short f2bf(float f) {
    unsigned u = __float_as_uint(f);
    u += 0x7FFF + ((u >> 16) & 1);
    return (unsigned short)(u >> 16);
}
__device__ __forceinline__ float bf2f(unsigned short s) {
    return __uint_as_float((unsigned)s << 16);
}

// ---------------------------------------------------------------------------
// CSR build: histogram -> exclusive scan -> fill
// ---------------------------------------------------------------------------
__global__ void edge_hist(const int* __restrict__ dst, int* __restrict__ cnt, int e) {
    int i = blockIdx.x * blockDim.x + threadIdx.x;
    if (i < e) atomicAdd(&cnt[dst[i]], 1);
}

__global__ void scan_excl(const int* __restrict__ cnt, int* __restrict__ row_ptr, int n) {
    const int CH = 40;
    __shared__ int sm[1024];
    int tid = threadIdx.x;
    int start = tid * CH;
    int local[CH];
    int s = 0;
    #pragma unroll
    for (int k = 0; k < CH; ++k) {
        int i = start + k;
        int v = (i < n) ? cnt[i] : 0;
        local[k] = s;
        s += v;
    }
    sm[tid] = s;
    __syncthreads();
    for (int off = 1; off < 1024; off <<= 1) {
        int t = (tid >= off) ? sm[tid - off] : 0;
        __syncthreads();
        sm[tid] += t;
        __syncthreads();
    }
    int base = sm[tid] - s;
    #pragma unroll
    for (int k = 0; k < CH; ++k) {
        int i = start + k;
        if (i < n) row_ptr[i] = base + local[k];
    }
    if (tid == 1023) row_ptr[n] = sm[1023];
}

__global__ void edge_fill(const int* __restrict__ src, const int* __restrict__ dst,
                          const int* __restrict__ row_ptr, int* __restrict__ fill,
                          int* __restrict__ csr_src, int e) {
    int i = blockIdx.x * blockDim.x + threadIdx.x;
    if (i < e) {
        int d = dst[i];
        int pos = row_ptr[d] + atomicAdd(&fill[d], 1);
        csr_src[pos] = src[i];
    }
}

// ---------------------------------------------------------------------------
// weight prep (all 3 layers in one dispatch): W[K][128] fp32 -> staged bf16
// hi/lo chunks (see round-5 layout comment).
// ---------------------------------------------------------------------------
__device__ __forceinline__ void wprep_one(const float* __restrict__ W,
                                          unsigned short* __restrict__ Bp,
                                          int i, int K) {
    int k = i >> 7, col = i & 127;
    float v = W[i];
    unsigned short hh = f2bf(v);
    unsigned short ll = f2bf(v - bf2f(hh));
    int t = k >> 6, rr = k & 63;
    int s = rr >> 5, r5 = rr & 31;
    int laneHi = r5 >> 3, j = r5 & 7;
    int lane = laneHi * 16 + (col & 15);
    int n = col >> 4;
    int U = (n * 2 + s) * 64 + lane;
    size_t idx = (size_t)t * 16384 + (size_t)U * 8 + j;
    Bp[idx] = hh;
    Bp[idx + 8192] = ll;
}

__global__ void wprep_all(const float* __restrict__ W1, const float* __restrict__ W2,
                          const float* __restrict__ W3, unsigned short* __restrict__ Bp1,
                          unsigned short* __restrict__ Bp2, unsigned short* __restrict__ Bp3) {
    int i = blockIdx.x * blockDim.x + threadIdx.x;
    const int n1 = F_IN * H, n2 = H * H;
    if (i < n1) { wprep_one(W1, Bp1, i, F_IN); return; }
    i -= n1;
    if (i < n2) { wprep_one(W2, Bp2, i, H); return; }
    i -= n2;
    if (i < n2) { wprep_one(W3, Bp3, i, H); }
}

// ---------------------------------------------------------------------------
// GEMM bf16x3 MFMA v5: h = A @ W + fused scores. Unroll-by-2 K loop,
// double-buffered LDS (1 barrier/chunk), double named-reg prefetch for A & B.
// nt = K/64 must be even (1280/64=20, 128/64=2: ok).
// ---------------------------------------------------------------------------
__device__ __forceinline__ void cvt8(float4 x, float4 y, short8& hi, short8& lo) {
    float f[8] = {x.x, x.y, x.z, x.w, y.x, y.y, y.z, y.w};
    #pragma unroll
    for (int j = 0; j < 8; ++j) {
        unsigned u = __float_as_uint(f[j]);
        unsigned short hh = (unsigned short)((u + 0x7FFF + ((u >> 16) & 1)) >> 16);
        hi[j] = (short)hh;
        float r = f[j] - __uint_as_float((unsigned)hh << 16);
        unsigned ur = __float_as_uint(r);
        lo[j] = (short)((ur + 0x7FFF + ((ur >> 16) & 1)) >> 16);
    }
}

__global__ __launch_bounds__(256) void gemm_fused(
    const float* __restrict__ A, const unsigned short* __restrict__ Bp,
    const float* __restrict__ a_src, const float* __restrict__ a_dst,
    unsigned short* __restrict__ hWb, float* __restrict__ hs,
    float* __restrict__ hd, int K)
{
    __shared__ __align__(16) unsigned short lds[2][16384];   // 2 x 32 KB
    const int tid  = threadIdx.x;
    const int lane = tid & 63, wv = tid >> 6;
    const int fr = lane & 15, q = lane >> 4;
    const int m0 = blockIdx.x * 64;
    const int row = m0 + wv * 16 + fr;
    const int nt = K >> 6;

    const uint4* gb = (const uint4*)Bp + tid;
    const float* Aptr = A + (size_t)row * K + q * 8;

    f32x4 acc0 = {}, acc1 = {}, acc2 = {}, acc3 = {},
          acc4 = {}, acc5 = {}, acc6 = {}, acc7 = {};

    uint4 bA0, bA1, bA2, bA3, bA4, bA5, bA6, bA7;
    uint4 bB0, bB1, bB2, bB3, bB4, bB5, bB6, bB7;
    float4 aA0, aA1, aA2, aA3, aB0, aB1, aB2, aB3;

#define LOADB(t, r0, r1, r2, r3, r4, r5, r6, r7)                                \
    { const uint4* g = gb + (size_t)(t) * 2048;                                 \
      r0 = g[0];    r1 = g[256];  r2 = g[512];  r3 = g[768];                    \
      r4 = g[1024]; r5 = g[1280]; r6 = g[1536]; r7 = g[1792]; }
#define LOADA(t, x0, x1, x2, x3)                                                \
    { const float* ap = Aptr + (size_t)(t) * 64;                                \
      x0 = *(const float4*)(ap);      x1 = *(const float4*)(ap + 4);            \
      x2 = *(const float4*)(ap + 32); x3 = *(const float4*)(ap + 36); }
#define STAGE(buf, r0, r1, r2, r3, r4, r5, r6, r7)                              \
    { uint4* lp = (uint4*)lds[buf] + tid;                                       \
      lp[0] = r0;    lp[256] = r1;  lp[512] = r2;  lp[768] = r3;                \
      lp[1024] = r4; lp[1280] = r5; lp[1536] = r6; lp[1792] = r7; }
#define MSTEP(buf, nn, accv, ss)                                                \
    { const short8 bh = *(const short8*)&lds[buf][(size_t)(((nn)*2+(ss))*64 + lane)*8];        \
      const short8 bl = *(const short8*)&lds[buf][(size_t)(((nn)*2+(ss))*64 + lane)*8 + 8192]; \
      accv = __builtin_amdgcn_mfma_f32_16x16x32_bf16(ah, bh, accv, 0, 0, 0);    \
      accv = __builtin_amdgcn_mfma_f32_16x16x32_bf16(ah, bl, accv, 0, 0, 0);    \
      accv = __builtin_amdgcn_mfma_f32_16x16x32_bf16(al, bh, accv, 0, 0, 0); }
#define COMPUTE(buf, x0, x1, x2, x3)                                            \
    { short8 ah, al;                                                            \
      cvt8(x0, x1, ah, al);                                                     \
      MSTEP(buf, 0, acc0, 0) MSTEP(buf, 1, acc1, 0) MSTEP(buf, 2, acc2, 0)      \
      MSTEP(buf, 3, acc3, 0) MSTEP(buf, 4, acc4, 0) MSTEP(buf, 5, acc5, 0)      \
      MSTEP(buf, 6, acc6, 0) MSTEP(buf, 7, acc7, 0)                             \
      cvt8(x2, x3, ah, al);                                                     \
      MSTEP(buf, 0, acc0, 1) MSTEP(buf, 1, acc1, 1) MSTEP(buf, 2, acc2, 1)      \
      MSTEP(buf, 3, acc3, 1) MSTEP(buf, 4, acc4, 1) MSTEP(buf, 5, acc5, 1)      \
      MSTEP(buf, 6, acc6, 1) MSTEP(buf, 7, acc7, 1) }

    LOADB(0, bA0, bA1, bA2, bA3, bA4, bA5, bA6, bA7);
    LOADA(0, aA0, aA1, aA2, aA3);

    for (int t = 0; t < nt; t += 2) {
        STAGE(0, bA0, bA1, bA2, bA3, bA4, bA5, bA6, bA7);
        LOADB(t + 1, bB0, bB1, bB2, bB3, bB4, bB5, bB6, bB7);
        LOADA(t + 1, aB0, aB1, aB2, aB3);
        __syncthreads();
        COMPUTE(0, aA0, aA1, aA2, aA3);

        STAGE(1, bB0, bB1, bB2, bB3, bB4, bB5, bB6, bB7);
        if (t + 2 < nt) {
            LOADB(t + 2, bA0, bA1, bA2, bA3, bA4, bA5, bA6, bA7);
            LOADA(t + 2, aA0, aA1, aA2, aA3);
        }
        __syncthreads();
        COMPUTE(1, aB0, aB1, aB2, aB3);
    }
#undef LOADB
#undef LOADA
#undef STAGE
#undef MSTEP
#undef COMPUTE

    // epilogue 1: bf16 h store. C/D layout col=lane&15, row=(lane>>4)*4+i
    const int rb = m0 + wv * 16 + q * 4;
#define EPI(nn, accv)                                                           \
    {                                                                           \
        _Pragma("unroll")                                                       \
        for (int i = 0; i < 4; ++i)                                             \
            hWb[(size_t)(rb + i) * H + (nn)*16 + fr] = f2bf(accv[i]);           \
    }
    EPI(0, acc0) EPI(1, acc1) EPI(2, acc2) EPI(3, acc3)
    EPI(4, acc4) EPI(5, acc5) EPI(6, acc6) EPI(7, acc7)
#undef EPI

    // epilogue 2: fused scores hs/hd from fp32 acc
    float asv[8], adv[8];
    #pragma unroll
    for (int n = 0; n < 8; ++n) {
        asv[n] = a_src[n * 16 + fr];
        adv[n] = a_dst[n * 16 + fr];
    }
    #pragma unroll
    for (int i = 0; i < 4; ++i) {
        float ss = acc0[i]*asv[0] + acc1[i]*asv[1] + acc2[i]*asv[2] + acc3[i]*asv[3]
                 + acc4[i]*asv[4] + acc5[i]*asv[5] + acc6[i]*asv[6] + acc7[i]*asv[7];
        float dd = acc0[i]*adv[0] + acc1[i]*adv[1] + acc2[i]*adv[2] + acc3[i]*adv[3]
                 + acc4[i]*adv[4] + acc5[i]*adv[5] + acc6[i]*adv[6] + acc7[i]*adv[7];
        #pragma unroll
        for (int off = 8; off; off >>= 1) {
            ss += __shfl_xor(ss, off);
            dd += __shfl_xor(dd, off);
        }
        if (fr == 0) { hs[rb + i] = ss; hd[rb + i] = dd; }
    }
}

// ---------------------------------------------------------------------------
// fused segment softmax + aggregation, one wave per dst node.
// Fast path: h-row gathers for first 16 edges issued BEFORE the softmax
// reduction (no data dependency) -> gather latency hides under shfl chain.
// ---------------------------------------------------------------------------
__device__ __forceinline__ float bfhi(unsigned u) { return __uint_as_float(u << 16); }
__device__ __forceinline__ float bflo(unsigned u) { return __uint_as_float(u & 0xffff0000u); }

__global__ void attn_agg(const unsigned short* __restrict__ hWb,
                         const float* __restrict__ hs, const float* __restrict__ hd,
                         const int* __restrict__ row_ptr, const int* __restrict__ csr_src,
                         const float* __restrict__ bias, float* __restrict__ out,
                         int n, int relu_flag) {
    int wv = (blockIdx.x * blockDim.x + threadIdx.x) >> 6;
    int lane = threadIdx.x & 63;
    if (wv >= n) return;
    int p0 = row_ptr[wv], p1 = row_ptr[wv + 1];
    int deg = p1 - p0;
    float hdi = hd[wv];
    float ax = 0.f, ay = 0.f;
    const unsigned* hb = (const unsigned*)hWb;     // 64 bf16-pairs per row

    if (deg <= 64) {
        int valid = (lane < deg);
        int sidx = valid ? csr_src[p0 + lane] : 0;

        // ---- issue first-16 row gathers (deg wave-uniform -> scalar branches)
#define PF(k) int s_##k = __shfl(sidx, k); unsigned u_##k = 0;                  \
              if (deg > k) u_##k = hb[(size_t)s_##k * 64 + lane];
        PF(0)  PF(1)  PF(2)  PF(3)  PF(4)  PF(5)  PF(6)  PF(7)
        PF(8)  PF(9)  PF(10) PF(11) PF(12) PF(13) PF(14) PF(15)
#undef PF

        // ---- softmax (overlaps with gathers in flight) ----
        float e = hs[sidx] + hdi;
        e = (e >= 0.f) ? e : NEG_SLOPE * e;
        float m = valid ? e : -3.4e38f;
        #pragma unroll
        for (int off = 32; off; off >>= 1) m = fmaxf(m, __shfl_xor(m, off));
        float pe = valid ? __expf(e - m) : 0.f;
        float dsum = pe;
        #pragma unroll
        for (int off = 32; off; off >>= 1) dsum += __shfl_xor(dsum, off);
        pe *= 1.f / (dsum + 1e-16f);

        // ---- accumulate prefetched 16 ----
#define AC(k) if (deg > k) { float aa = __shfl(pe, k);                          \
                             ax += aa * bfhi(u_##k); ay += aa * bflo(u_##k); }
        AC(0)  AC(1)  AC(2)  AC(3)  AC(4)  AC(5)  AC(6)  AC(7)
        AC(8)  AC(9)  AC(10) AC(11) AC(12) AC(13) AC(14) AC(15)
#undef AC

        // ---- tail (deg > 16), 4 gathers in flight ----
        for (int j = 16; j < deg; j += 4) {
            int t0 = __shfl(sidx, j);
            int t1 = (j + 1 < deg) ? __shfl(sidx, j + 1) : t0;
            int t2 = (j + 2 < deg) ? __shfl(sidx, j + 2) : t0;
            int t3 = (j + 3 < deg) ? __shfl(sidx, j + 3) : t0;
            unsigned v0 = hb[(size_t)t0 * 64 + lane];
            unsigned v1 = hb[(size_t)t1 * 64 + lane];
            unsigned v2 = hb[(size_t)t2 * 64 + lane];
            unsigned v3 = hb[(size_t)t3 * 64 + lane];
            float b0 = __shfl(pe, j);
            float b1 = (j + 1 < deg) ? __shfl(pe, j + 1) : 0.f;
            float b2 = (j + 2 < deg) ? __shfl(pe, j + 2) : 0.f;
            float b3 = (j + 3 < deg) ? __shfl(pe, j + 3) : 0.f;
            ax += b0 * bfhi(v0); ay += b0 * bflo(v0);
            ax += b1 * bfhi(v1); ay += b1 * bflo(v1);
            ax += b2 * bfhi(v2); ay += b2 * bflo(v2);
            ax += b3 * bfhi(v3); ay += b3 * bflo(v3);
        }
    } else {
        // general path (deg > 64)
        float m = -3.4e38f;
        for (int p = p0 + lane; p < p1; p += 64) {
            float e = hs[csr_src[p]] + hdi;
            e = (e >= 0.f) ? e : NEG_SLOPE * e;
            m = fmaxf(m, e);
        }
        #pragma unroll
        for (int off = 32; off; off >>= 1) m = fmaxf(m, __shfl_xor(m, off));
        float dsum = 0.f;
        for (int p = p0 + lane; p < p1; p += 64) {
            float e = hs[csr_src[p]] + hdi;
            e = (e >= 0.f) ? e : NEG_SLOPE * e;
            dsum += __expf(e - m);
        }
        #pragma unroll
        for (int off = 32; off; off >>= 1) dsum += __shfl_xor(dsum, off);
        float inv = 1.f / (dsum + 1e-16f);
        for (int p = p0; p < p1; ++p) {
            int s = csr_src[p];
            float e = hs[s] + hdi;
            e = (e >= 0.f) ? e : NEG_SLOPE * e;
            float alpha = __expf(e - m) * inv;
            unsigned u = hb[(size_t)s * 64 + lane];
            ax += alpha * bfhi(u); ay += alpha * bflo(u);
        }
    }
    float2 bv = *(const float2*)&bias[2 * lane];
    float o0 = ax + bv.x;
    float o1 = ay + bv.y;
    if (relu_flag) { o0 = fmaxf(o0, 0.f); o1 = fmaxf(o1, 0.f); }
    float2 ov; ov.x = o0; ov.y = o1;
    *(float2*)&out[(size_t)wv * H + 2 * lane] = ov;
}

// ---------------------------------------------------------------------------
// global mean pool per graph, two-stage (batch sorted -> binary search)
// ---------------------------------------------------------------------------
__device__ __forceinline__ void graph_range(const int* __restrict__ batch, int n,
                                            int g, int& start, int& end) {
    int lo = 0, hi = n;
    while (lo < hi) { int mid = (lo + hi) >> 1; if (batch[mid] < g) lo = mid + 1; else hi = mid; }
    start = lo;
    lo = start; hi = n;
    while (lo < hi) { int mid = (lo + hi) >> 1; if (batch[mid] < g + 1) lo = mid + 1; else hi = mid; }
    end = lo;
}

__global__ void pool_part(const float* __restrict__ h, const int* __restrict__ batch,
                          float* __restrict__ part, int n) {
    int g = blockIdx.x >> 3, c = blockIdx.x & 7;
    int f = threadIdx.x;
    int start, end;
    graph_range(batch, n, g, start, end);
    int len = end - start;
    int cs = start + (len * c) / 8, ce = start + (len * (c + 1)) / 8;
    float acc = 0.f;
    for (int i = cs; i < ce; ++i) acc += h[(size_t)i * H + f];
    part[((size_t)g * 8 + c) * H + f] = acc;
}

__global__ void pool_final(const float* __restrict__ part, const int* __restrict__ batch,
                           float* __restrict__ pooled, int n) {
    int g = blockIdx.x;
    int f = threadIdx.x;
    int start, end;
    graph_range(batch, n, g, start, end);
    float s = 0.f;
    #pragma unroll
    for (int c = 0; c < 8; ++c) s += part[((size_t)g * 8 + c) * H + f];
    float cnt = (float)(end - start);
    pooled[g * H + f] = s / fmaxf(cnt, 1.f);
}

// ---------------------------------------------------------------------------
// FC1 + BN(eval) + ReLU : z[64][1024]
// ---------------------------------------------------------------------------
__global__ void fc1_bn_relu(const float* __restrict__ pooled, const float* __restrict__ W,
                            const float* __restrict__ b, const float* __restrict__ bng,
                            const float* __restrict__ bnb, const float* __restrict__ bnrm,
                            const float* __restrict__ bnrv, float* __restrict__ z) {
    int g = blockIdx.x >> 2;
    int j = ((blockIdx.x & 3) << 8) + threadIdx.x;
    const float* pr = pooled + g * H;
    float acc = b[j];
    #pragma unroll 8
    for (int k = 0; k < H; ++k) acc += pr[k] * W[k * FC1D + j];
    float v = (acc - bnrm[j]) * rsqrtf(bnrv[j] + BN_EPS) * bng[j] + bnb[j];
    z[g * FC1D + j] = fmaxf(v, 0.f);
}

// ---------------------------------------------------------------------------
// FC2 + sigmoid : out[64][273]
// ---------------------------------------------------------------------------
__global__ void fc2_sig(const float* __restrict__ z, const float* __restrict__ W,
                        const float* __restrict__ b, float* __restrict__ out) {
    int g = blockIdx.x;
    int j = threadIdx.x;
    if (j >= OUTD) return;
    const float* zr = z + g * FC1D;
    float acc = b[j];
    #pragma unroll 4
    for (int k = 0; k < FC1D; ++k) acc += zr[k] * W[k * OUTD + j];
    out[g * OUTD + j] = 1.f / (1.f + __expf(-acc));
}

// ---------------------------------------------------------------------------
extern "C" void kernel_launch(void* const* d_in, const int* in_sizes, int n_in,
                              void* d_out, int out_size, void* d_ws, size_t ws_size,
                              hipStream_t stream) {
    const float* x     = (const float*)d_in[0];
    const int*   eidx  = (const int*)d_in[1];
    const int*   batch = (const int*)d_in[2];
    const float* W1 = (const float*)d_in[3];  const float* b1 = (const float*)d_in[4];
    const float* as1 = (const float*)d_in[5]; const float* ad1 = (const float*)d_in[6];
    const float* W2 = (const float*)d_in[7];  const float* b2 = (const float*)d_in[8];
    const float* as2 = (const float*)d_in[9]; const float* ad2 = (const float*)d_in[10];
    const float* W3 = (const float*)d_in[11]; const float* b3 = (const float*)d_in[12];
    const float* as3 = (const float*)d_in[13]; const float* ad3 = (const float*)d_in[14];
    const float* fc1W = (const float*)d_in[15]; const float* fc1b = (const float*)d_in[16];
    const float* bng = (const float*)d_in[17];  const float* bnb = (const float*)d_in[18];
    const float* bnrm = (const float*)d_in[19]; const float* bnrv = (const float*)d_in[20];
    const float* fc2W = (const float*)d_in[21]; const float* fc2b = (const float*)d_in[22];
    const int* src = eidx;
    const int* dst = eidx + N_EDGES;

    // workspace layout
    float* hA      = (float*)d_ws;                     // N*H fp32
    float* hs      = hA + (size_t)N_NODES * H;         // N
    float* hd      = hs + N_NODES;                     // N
    float* pooled  = hd + N_NODES;                     // G*H
    float* part    = pooled + NG * H;                  // G*8*H
    float* z       = part + NG * 8 * H;                // G*1024
    unsigned short* hWb = (unsigned short*)(z + NG * FC1D);    // N*H bf16
    unsigned short* Bp1 = hWb + (size_t)N_NODES * H;           // 20 chunks * 16384
    unsigned short* Bp2 = Bp1 + (size_t)(F_IN / 64) * 16384;   // 2 chunks
    unsigned short* Bp3 = Bp2 + (size_t)(H / 64) * 16384;      // 2 chunks
    int*   row_ptr = (int*)(Bp3 + (size_t)(H / 64) * 16384);   // N+1
    int*   row_cnt = row_ptr + (N_NODES + 1);          // N
    int*   csr_src = row_cnt + N_NODES;                // E

    const int EB = (N_EDGES + 255) / 256;
    const int NW = (N_NODES * 64 + 255) / 256;
    const int GB = N_NODES / 64;

    // ---- weight prep (one dispatch) ----
    const int WTOT = F_IN * H + 2 * H * H;
    wprep_all<<<(WTOT + 255) / 256, 256, 0, stream>>>(W1, W2, W3, Bp1, Bp2, Bp3);

    // ---- CSR build (by dst) ----
    hipMemsetAsync(row_cnt, 0, N_NODES * sizeof(int), stream);
    edge_hist<<<EB, 256, 0, stream>>>(dst, row_cnt, N_EDGES);
    scan_excl<<<1, 1024, 0, stream>>>(row_cnt, row_ptr, N_NODES);
    hipMemsetAsync(row_cnt, 0, N_NODES * sizeof(int), stream);
    edge_fill<<<EB, 256, 0, stream>>>(src, dst, row_ptr, row_cnt, csr_src, N_EDGES);

    // ---- layer 1 ----
    gemm_fused<<<GB, 256, 0, stream>>>(x, Bp1, as1, ad1, hWb, hs, hd, F_IN);
    attn_agg<<<NW, 256, 0, stream>>>(hWb, hs, hd, row_ptr, csr_src, b1, hA, N_NODES, 1);
    // ---- layer 2 ----
    gemm_fused<<<GB, 256, 0, stream>>>(hA, Bp2, as2, ad2, hWb, hs, hd, H);
    attn_agg<<<NW, 256, 0, stream>>>(hWb, hs, hd, row_ptr, csr_src, b2, hA, N_NODES, 1);
    // ---- layer 3 (no relu) ----
    gemm_fused<<<GB, 256, 0, stream>>>(hA, Bp3, as3, ad3, hWb, hs, hd, H);
    attn_agg<<<NW, 256, 0, stream>>>(hWb, hs, hd, row_ptr, csr_src, b3, hA, N_NODES, 0);

    // ---- head ----
    pool_part<<<NG * 8, H, 0, stream>>>(hA, batch, part, N_NODES);
    pool_final<<<NG, H, 0, stream>>>(part, batch, pooled, N_NODES);
    fc1_bn_relu<<<NG * 4, 256, 0, stream>>>(pooled, fc1W, fc1b, bng, bnb, bnrm, bnrv, z);
    fc2_sig<<<NG, 320, 0, stream>>>(z, fc2W, fc2b, (float*)d_out);
}

// Round 9
// 739.038 us; speedup vs baseline: 1.5549x; 1.0050x over previous
//
#include <hip/hip_runtime.h>
#include <math.h>

// Problem constants (from reference)
#define N_NODES 40000
#define N_EDGES 640000
#define F_IN    1280
#define H       128
#define NG      64
#define OUTD    273
#define FC1D    1024
#define NEG_SLOPE 0.2f
#define BN_EPS  1e-5f

typedef __attribute__((ext_vector_type(8))) short short8;
typedef __attribute__((ext_vector_type(4))) float f32x4;

__device__ __forceinline__ unsigned short f2bf(float f) {
    unsigned u = __float_as_uint(f);
    u += 0x7FFF + ((u >> 16) & 1);
    return (unsigned short)(u >> 16);
}
__device__ __forceinline__ float bf2f(unsigned short s) {
    return __uint_as_float((unsigned)s << 16);
}

// ---------------------------------------------------------------------------
// CSR build: histogram -> exclusive scan -> fill
// ---------------------------------------------------------------------------
__global__ void edge_hist(const int* __restrict__ dst, int* __restrict__ cnt, int e) {
    int i = blockIdx.x * blockDim.x + threadIdx.x;
    if (i < e) atomicAdd(&cnt[dst[i]], 1);
}

__global__ void scan_excl(const int* __restrict__ cnt, int* __restrict__ row_ptr, int n) {
    const int CH = 40;
    __shared__ int sm[1024];
    int tid = threadIdx.x;
    int start = tid * CH;
    int local[CH];
    int s = 0;
    #pragma unroll
    for (int k = 0; k < CH; ++k) {
        int i = start + k;
        int v = (i < n) ? cnt[i] : 0;
        local[k] = s;
        s += v;
    }
    sm[tid] = s;
    __syncthreads();
    for (int off = 1; off < 1024; off <<= 1) {
        int t = (tid >= off) ? sm[tid - off] : 0;
        __syncthreads();
        sm[tid] += t;
        __syncthreads();
    }
    int base = sm[tid] - s;
    #pragma unroll
    for (int k = 0; k < CH; ++k) {
        int i = start + k;
        if (i < n) row_ptr[i] = base + local[k];
    }
    if (tid == 1023) row_ptr[n] = sm[1023];
}

__global__ void edge_fill(const int* __restrict__ src, const int* __restrict__ dst,
                          const int* __restrict__ row_ptr, int* __restrict__ fill,
                          int* __restrict__ csr_src, int e) {
    int i = blockIdx.x * blockDim.x + threadIdx.x;
    if (i < e) {
        int d = dst[i];
        int pos = row_ptr[d] + atomicAdd(&fill[d], 1);
        csr_src[pos] = src[i];
    }
}

// ---------------------------------------------------------------------------
// weight prep (all 3 layers, one dispatch): W[K][128] fp32 -> staged bf16
// hi/lo chunks (chunk-linear; see round-5 layout comment).
// ---------------------------------------------------------------------------
__device__ __forceinline__ void wprep_one(const float* __restrict__ W,
                                          unsigned short* __restrict__ Bp,
                                          int i, int K) {
    int k = i >> 7, col = i & 127;
    float v = W[i];
    unsigned short hh = f2bf(v);
    unsigned short ll = f2bf(v - bf2f(hh));
    int t = k >> 6, rr = k & 63;
    int s = rr >> 5, r5 = rr & 31;
    int laneHi = r5 >> 3, j = r5 & 7;
    int lane = laneHi * 16 + (col & 15);
    int n = col >> 4;
    int U = (n * 2 + s) * 64 + lane;
    size_t idx = (size_t)t * 16384 + (size_t)U * 8 + j;
    Bp[idx] = hh;
    Bp[idx + 8192] = ll;
}

__global__ void wprep_all(const float* __restrict__ W1, const float* __restrict__ W2,
                          const float* __restrict__ W3, unsigned short* __restrict__ Bp1,
                          unsigned short* __restrict__ Bp2, unsigned short* __restrict__ Bp3) {
    int i = blockIdx.x * blockDim.x + threadIdx.x;
    const int n1 = F_IN * H, n2 = H * H;
    if (i < n1) { wprep_one(W1, Bp1, i, F_IN); return; }
    i -= n1;
    if (i < n2) { wprep_one(W2, Bp2, i, H); return; }
    i -= n2;
    if (i < n2) { wprep_one(W3, Bp3, i, H); }
}

// ---------------------------------------------------------------------------
// GEMM bf16x3 MFMA v6: h = A @ W + fused scores.
// SINGLE 32 KB LDS buffer (occupancy ~3 blocks/CU) + A AND B register-
// prefetched one chunk ahead (2 named-reg sets, unroll-by-2, 2 barriers/chunk).
// nt = K/64 must be even (20, 2: ok).
// ---------------------------------------------------------------------------
__device__ __forceinline__ void cvt8(float4 x, float4 y, short8& hi, short8& lo) {
    float f[8] = {x.x, x.y, x.z, x.w, y.x, y.y, y.z, y.w};
    #pragma unroll
    for (int j = 0; j < 8; ++j) {
        unsigned u = __float_as_uint(f[j]);
        unsigned short hh = (unsigned short)((u + 0x7FFF + ((u >> 16) & 1)) >> 16);
        hi[j] = (short)hh;
        float r = f[j] - __uint_as_float((unsigned)hh << 16);
        unsigned ur = __float_as_uint(r);
        lo[j] = (short)((ur + 0x7FFF + ((ur >> 16) & 1)) >> 16);
    }
}

__global__ __launch_bounds__(256) void gemm_fused(
    const float* __restrict__ A, const unsigned short* __restrict__ Bp,
    const float* __restrict__ a_src, const float* __restrict__ a_dst,
    unsigned short* __restrict__ hWb, float* __restrict__ hs,
    float* __restrict__ hd, int K)
{
    __shared__ __align__(16) unsigned short lds[16384];   // 32 KB, single buffer
    const int tid  = threadIdx.x;
    const int lane = tid & 63, wv = tid >> 6;
    const int fr = lane & 15, q = lane >> 4;
    const int m0 = blockIdx.x * 64;
    const int row = m0 + wv * 16 + fr;
    const int nt = K >> 6;

    const uint4* gb = (const uint4*)Bp + tid;
    const float* Aptr = A + (size_t)row * K + q * 8;

    f32x4 acc0 = {}, acc1 = {}, acc2 = {}, acc3 = {},
          acc4 = {}, acc5 = {}, acc6 = {}, acc7 = {};

    uint4 bA0, bA1, bA2, bA3, bA4, bA5, bA6, bA7;
    uint4 bB0, bB1, bB2, bB3, bB4, bB5, bB6, bB7;
    float4 aA0, aA1, aA2, aA3, aB0, aB1, aB2, aB3;

#define LOADB(t, r0, r1, r2, r3, r4, r5, r6, r7)                                \
    { const uint4* g = gb + (size_t)(t) * 2048;                                 \
      r0 = g[0];    r1 = g[256];  r2 = g[512];  r3 = g[768];                    \
      r4 = g[1024]; r5 = g[1280]; r6 = g[1536]; r7 = g[1792]; }
#define LOADA(t, x0, x1, x2, x3)                                                \
    { const float* ap = Aptr + (size_t)(t) * 64;                                \
      x0 = *(const float4*)(ap);      x1 = *(const float4*)(ap + 4);            \
      x2 = *(const float4*)(ap + 32); x3 = *(const float4*)(ap + 36); }
#define STAGE(r0, r1, r2, r3, r4, r5, r6, r7)                                   \
    { uint4* lp = (uint4*)lds + tid;                                            \
      lp[0] = r0;    lp[256] = r1;  lp[512] = r2;  lp[768] = r3;                \
      lp[1024] = r4; lp[1280] = r5; lp[1536] = r6; lp[1792] = r7; }
#define MSTEP(nn, accv, ss)                                                     \
    { const short8 bh = *(const short8*)&lds[(size_t)(((nn)*2+(ss))*64 + lane)*8];        \
      const short8 bl = *(const short8*)&lds[(size_t)(((nn)*2+(ss))*64 + lane)*8 + 8192]; \
      accv = __builtin_amdgcn_mfma_f32_16x16x32_bf16(ah, bh, accv, 0, 0, 0);    \
      accv = __builtin_amdgcn_mfma_f32_16x16x32_bf16(ah, bl, accv, 0, 0, 0);    \
      accv = __builtin_amdgcn_mfma_f32_16x16x32_bf16(al, bh, accv, 0, 0, 0); }
#define COMPUTE(x0, x1, x2, x3)                                                 \
    { short8 ah, al;                                                            \
      cvt8(x0, x1, ah, al);                                                     \
      MSTEP(0, acc0, 0) MSTEP(1, acc1, 0) MSTEP(2, acc2, 0)                     \
      MSTEP(3, acc3, 0) MSTEP(4, acc4, 0) MSTEP(5, acc5, 0)                     \
      MSTEP(6, acc6, 0) MSTEP(7, acc7, 0)                                       \
      cvt8(x2, x3, ah, al);                                                     \
      MSTEP(0, acc0, 1) MSTEP(1, acc1, 1) MSTEP(2, acc2, 1)                     \
      MSTEP(3, acc3, 1) MSTEP(4, acc4, 1) MSTEP(5, acc5, 1)                     \
      MSTEP(6, acc6, 1) MSTEP(7, acc7, 1) }

    LOADB(0, bA0, bA1, bA2, bA3, bA4, bA5, bA6, bA7);
    LOADA(0, aA0, aA1, aA2, aA3);

    for (int t = 0; t < nt; t += 2) {
        // chunk t (regs set A)
        STAGE(bA0, bA1, bA2, bA3, bA4, bA5, bA6, bA7);
        LOADB(t + 1, bB0, bB1, bB2, bB3, bB4, bB5, bB6, bB7);
        LOADA(t + 1, aB0, aB1, aB2, aB3);
        __syncthreads();
        COMPUTE(aA0, aA1, aA2, aA3);
        __syncthreads();
        // chunk t+1 (regs set B)
        STAGE(bB0, bB1, bB2, bB3, bB4, bB5, bB6, bB7);
        if (t + 2 < nt) {
            LOADB(t + 2, bA0, bA1, bA2, bA3, bA4, bA5, bA6, bA7);
            LOADA(t + 2, aA0, aA1, aA2, aA3);
        }
        __syncthreads();
        COMPUTE(aB0, aB1, aB2, aB3);
        __syncthreads();
    }
#undef LOADB
#undef LOADA
#undef STAGE
#undef MSTEP
#undef COMPUTE

    // epilogue 1: bf16 h store. C/D layout col=lane&15, row=(lane>>4)*4+i
    const int rb = m0 + wv * 16 + q * 4;
#define EPI(nn, accv)                                                           \
    {                                                                           \
        _Pragma("unroll")                                                       \
        for (int i = 0; i < 4; ++i)                                             \
            hWb[(size_t)(rb + i) * H + (nn)*16 + fr] = f2bf(accv[i]);           \
    }
    EPI(0, acc0) EPI(1, acc1) EPI(2, acc2) EPI(3, acc3)
    EPI(4, acc4) EPI(5, acc5) EPI(6, acc6) EPI(7, acc7)
#undef EPI

    // epilogue 2: fused scores hs/hd from fp32 acc
    float asv[8], adv[8];
    #pragma unroll
    for (int n = 0; n < 8; ++n) {
        asv[n] = a_src[n * 16 + fr];
        adv[n] = a_dst[n * 16 + fr];
    }
    #pragma unroll
    for (int i = 0; i < 4; ++i) {
        float ss = acc0[i]*asv[0] + acc1[i]*asv[1] + acc2[i]*asv[2] + acc3[i]*asv[3]
                 + acc4[i]*asv[4] + acc5[i]*asv[5] + acc6[i]*asv[6] + acc7[i]*asv[7];
        float dd = acc0[i]*adv[0] + acc1[i]*adv[1] + acc2[i]*adv[2] + acc3[i]*adv[3]
                 + acc4[i]*adv[4] + acc5[i]*adv[5] + acc6[i]*adv[6] + acc7[i]*adv[7];
        #pragma unroll
        for (int off = 8; off; off >>= 1) {
            ss += __shfl_xor(ss, off);
            dd += __shfl_xor(dd, off);
        }
        if (fr == 0) { hs[rb + i] = ss; hd[rb + i] = dd; }
    }
}

// ---------------------------------------------------------------------------
// fused segment softmax + aggregation, one wave per dst node.
// ORDER FIX vs round-7: hs[sidx] (the load softmax depends on) is issued
// BEFORE the 16 h-row gathers, so the softmax waits at vmcnt(16) and the
// gathers stay in flight across the shfl chain.
// ---------------------------------------------------------------------------
__device__ __forceinline__ float bfhi(unsigned u) { return __uint_as_float(u << 16); }
__device__ __forceinline__ float bflo(unsigned u) { return __uint_as_float(u & 0xffff0000u); }

__global__ void attn_agg(const unsigned short* __restrict__ hWb,
                         const float* __restrict__ hs, const float* __restrict__ hd,
                         const int* __restrict__ row_ptr, const int* __restrict__ csr_src,
                         const float* __restrict__ bias, float* __restrict__ out,
                         int n, int relu_flag) {
    int wv = (blockIdx.x * blockDim.x + threadIdx.x) >> 6;
    int lane = threadIdx.x & 63;
    if (wv >= n) return;
    int p0 = row_ptr[wv], p1 = row_ptr[wv + 1];
    int deg = p1 - p0;
    float hdi = hd[wv];
    float ax = 0.f, ay = 0.f;
    const unsigned* hb = (const unsigned*)hWb;     // 64 bf16-pairs per row

    if (deg <= 64) {
        int valid = (lane < deg);
        int sidx = valid ? csr_src[p0 + lane] : 0;
        float hsv = hs[sidx];                      // DEPENDENT load first

        // ---- issue first-16 row gathers AFTER hsv (latency hides under softmax)
#define PF(k) int s_##k = __shfl(sidx, k); unsigned u_##k = 0;                  \
              if (deg > k) u_##k = hb[(size_t)s_##k * 64 + lane];
        PF(0)  PF(1)  PF(2)  PF(3)  PF(4)  PF(5)  PF(6)  PF(7)
        PF(8)  PF(9)  PF(10) PF(11) PF(12) PF(13) PF(14) PF(15)
#undef PF

        // ---- softmax (waits only on hsv; 16 gathers in flight) ----
        float e = hsv + hdi;
        e = (e >= 0.f) ? e : NEG_SLOPE * e;
        float m = valid ? e : -3.4e38f;
        #pragma unroll
        for (int off = 32; off; off >>= 1) m = fmaxf(m, __shfl_xor(m, off));
        float pe = valid ? __expf(e - m) : 0.f;
        float dsum = pe;
        #pragma unroll
        for (int off = 32; off; off >>= 1) dsum += __shfl_xor(dsum, off);
        pe *= 1.f / (dsum + 1e-16f);

        // ---- accumulate prefetched 16 ----
#define AC(k) if (deg > k) { float aa = __shfl(pe, k);                          \
                             ax += aa * bfhi(u_##k); ay += aa * bflo(u_##k); }
        AC(0)  AC(1)  AC(2)  AC(3)  AC(4)  AC(5)  AC(6)  AC(7)
        AC(8)  AC(9)  AC(10) AC(11) AC(12) AC(13) AC(14) AC(15)
#undef AC

        // ---- tail (deg > 16), 4 gathers in flight ----
        for (int j = 16; j < deg; j += 4) {
            int t0 = __shfl(sidx, j);
            int t1 = (j + 1 < deg) ? __shfl(sidx, j + 1) : t0;
            int t2 = (j + 2 < deg) ? __shfl(sidx, j + 2) : t0;
            int t3 = (j + 3 < deg) ? __shfl(sidx, j + 3) : t0;
            unsigned v0 = hb[(size_t)t0 * 64 + lane];
            unsigned v1 = hb[(size_t)t1 * 64 + lane];
            unsigned v2 = hb[(size_t)t2 * 64 + lane];
            unsigned v3 = hb[(size_t)t3 * 64 + lane];
            float b0 = __shfl(pe, j);
            float b1 = (j + 1 < deg) ? __shfl(pe, j + 1) : 0.f;
            float b2 = (j + 2 < deg) ? __shfl(pe, j + 2) : 0.f;
            float b3 = (j + 3 < deg) ? __shfl(pe, j + 3) : 0.f;
            ax += b0 * bfhi(v0); ay += b0 * bflo(v0);
            ax += b1 * bfhi(v1); ay += b1 * bflo(v1);
            ax += b2 * bfhi(v2); ay += b2 * bflo(v2);
            ax += b3 * bfhi(v3); ay += b3 * bflo(v3);
        }
    } else {
        // general path (deg > 64)
        float m = -3.4e38f;
        for (int p = p0 + lane; p < p1; p += 64) {
            float e = hs[csr_src[p]] + hdi;
            e = (e >= 0.f) ? e : NEG_SLOPE * e;
            m = fmaxf(m, e);
        }
        #pragma unroll
        for (int off = 32; off; off >>= 1) m = fmaxf(m, __shfl_xor(m, off));
        float dsum = 0.f;
        for (int p = p0 + lane; p < p1; p += 64) {
            float e = hs[csr_src[p]] + hdi;
            e = (e >= 0.f) ? e : NEG_SLOPE * e;
            dsum += __expf(e - m);
        }
        #pragma unroll
        for (int off = 32; off; off >>= 1) dsum += __shfl_xor(dsum, off);
        float inv = 1.f / (dsum + 1e-16f);
        for (int p = p0; p < p1; ++p) {
            int s = csr_src[p];
            float e = hs[s] + hdi;
            e = (e >= 0.f) ? e : NEG_SLOPE * e;
            float alpha = __expf(e - m) * inv;
            unsigned u = hb[(size_t)s * 64 + lane];
            ax += alpha * bfhi(u); ay += alpha * bflo(u);
        }
    }
    float2 bv = *(const float2*)&bias[2 * lane];
    float o0 = ax + bv.x;
    float o1 = ay + bv.y;
    if (relu_flag) { o0 = fmaxf(o0, 0.f); o1 = fmaxf(o1, 0.f); }
    float2 ov; ov.x = o0; ov.y = o1;
    *(float2*)&out[(size_t)wv * H + 2 * lane] = ov;
}

// ---------------------------------------------------------------------------
// global mean pool, stage 1: per-graph 8-way partial sums
// ---------------------------------------------------------------------------
__device__ __forceinline__ void graph_range(const int* __restrict__ batch, int n,
                                            int g, int& start, int& end) {
    int lo = 0, hi = n;
    while (lo < hi) { int mid = (lo + hi) >> 1; if (batch[mid] < g) lo = mid + 1; else hi = mid; }
    start = lo;
    lo = start; hi = n;
    while (lo < hi) { int mid = (lo + hi) >> 1; if (batch[mid] < g + 1) lo = mid + 1; else hi = mid; }
    end = lo;
}

__global__ void pool_part(const float* __restrict__ h, const int* __restrict__ batch,
                          float* __restrict__ part, int n) {
    int g = blockIdx.x >> 3, c = blockIdx.x & 7;
    int f = threadIdx.x;
    int start, end;
    graph_range(batch, n, g, start, end);
    int len = end - start;
    int cs = start + (len * c) / 8, ce = start + (len * (c + 1)) / 8;
    float acc = 0.f;
    for (int i = cs; i < ce; ++i) acc += h[(size_t)i * H + f];
    part[((size_t)g * 8 + c) * H + f] = acc;
}

// ---------------------------------------------------------------------------
// pool finish + FC1 + BN(eval) + ReLU fused : z[64][1024]
// grid NG*4 x 256; each block rebuilds its graph's pooled row in LDS (cheap)
// ---------------------------------------------------------------------------
__global__ void fc1_bn_relu(const float* __restrict__ part, const int* __restrict__ batch,
                            const float* __restrict__ W, const float* __restrict__ b,
                            const float* __restrict__ bng, const float* __restrict__ bnb,
                            const float* __restrict__ bnrm, const float* __restrict__ bnrv,
                            float* __restrict__ z, int n) {
    __shared__ float pr[H];
    int g = blockIdx.x >> 2;
    int tid = threadIdx.x;
    if (tid < H) {
        int start, end;
        graph_range(batch, n, g, start, end);
        float s = 0.f;
        #pragma unroll
        for (int c = 0; c < 8; ++c) s += part[((size_t)g * 8 + c) * H + tid];
        pr[tid] = s / fmaxf((float)(end - start), 1.f);
    }
    __syncthreads();
    int j = ((blockIdx.x & 3) << 8) + tid;
    float acc = b[j];
    #pragma unroll 8
    for (int k = 0; k < H; ++k) acc += pr[k] * W[k * FC1D + j];
    float v = (acc - bnrm[j]) * rsqrtf(bnrv[j] + BN_EPS) * bng[j] + bnb[j];
    z[g * FC1D + j] = fmaxf(v, 0.f);
}

// ---------------------------------------------------------------------------
// FC2 + sigmoid : out[64][273]
// ---------------------------------------------------------------------------
__global__ void fc2_sig(const float* __restrict__ z, const float* __restrict__ W,
                        const float* __restrict__ b, float* __restrict__ out) {
    int g = blockIdx.x;
    int j = threadIdx.x;
    if (j >= OUTD) return;
    const float* zr = z + g * FC1D;
    float acc = b[j];
    #pragma unroll 4
    for (int k = 0; k < FC1D; ++k) acc += zr[k] * W[k * OUTD + j];
    out[g * OUTD + j] = 1.f / (1.f + __expf(-acc));
}

// ---------------------------------------------------------------------------
extern "C" void kernel_launch(void* const* d_in, const int* in_sizes, int n_in,
                              void* d_out, int out_size, void* d_ws, size_t ws_size,
                              hipStream_t stream) {
    const float* x     = (const float*)d_in[0];
    const int*   eidx  = (const int*)d_in[1];
    const int*   batch = (const int*)d_in[2];
    const float* W1 = (const float*)d_in[3];  const float* b1 = (const float*)d_in[4];
    const float* as1 = (const float*)d_in[5]; const float* ad1 = (const float*)d_in[6];
    const float* W2 = (const float*)d_in[7];  const float* b2 = (const float*)d_in[8];
    const float* as2 = (const float*)d_in[9]; const float* ad2 = (const float*)d_in[10];
    const float* W3 = (const float*)d_in[11]; const float* b3 = (const float*)d_in[12];
    const float* as3 = (const float*)d_in[13]; const float* ad3 = (const float*)d_in[14];
    const float* fc1W = (const float*)d_in[15]; const float* fc1b = (const float*)d_in[16];
    const float* bng = (const float*)d_in[17];  const float* bnb = (const float*)d_in[18];
    const float* bnrm = (const float*)d_in[19]; const float* bnrv = (const float*)d_in[20];
    const float* fc2W = (const float*)d_in[21]; const float* fc2b = (const float*)d_in[22];
    const int* src = eidx;
    const int* dst = eidx + N_EDGES;

    // workspace layout
    float* hA      = (float*)d_ws;                     // N*H fp32
    float* hs      = hA + (size_t)N_NODES * H;         // N
    float* hd      = hs + N_NODES;                     // N
    float* part    = hd + N_NODES;                     // G*8*H
    float* z       = part + NG * 8 * H;                // G*1024
    unsigned short* hWb = (unsigned short*)(z + NG * FC1D);    // N*H bf16
    unsigned short* Bp1 = hWb + (size_t)N_NODES * H;           // 20 chunks * 16384
    unsigned short* Bp2 = Bp1 + (size_t)(F_IN / 64) * 16384;   // 2 chunks
    unsigned short* Bp3 = Bp2 + (size_t)(H / 64) * 16384;      // 2 chunks
    int*   row_ptr = (int*)(Bp3 + (size_t)(H / 64) * 16384);   // N+1
    int*   row_cnt = row_ptr + (N_NODES + 1);          // N
    int*   csr_src = row_cnt + N_NODES;                // E

    const int EB = (N_EDGES + 255) / 256;
    const int NW = (N_NODES * 64 + 255) / 256;
    const int GB = N_NODES / 64;

    // ---- weight prep (one dispatch) ----
    const int WTOT = F_IN * H + 2 * H * H;
    wprep_all<<<(WTOT + 255) / 256, 256, 0, stream>>>(W1, W2, W3, Bp1, Bp2, Bp3);

    // ---- CSR build (by dst) ----
    hipMemsetAsync(row_cnt, 0, N_NODES * sizeof(int), stream);
    edge_hist<<<EB, 256, 0, stream>>>(dst, row_cnt, N_EDGES);
    scan_excl<<<1, 1024, 0, stream>>>(row_cnt, row_ptr, N_NODES);
    hipMemsetAsync(row_cnt, 0, N_NODES * sizeof(int), stream);
    edge_fill<<<EB, 256, 0, stream>>>(src, dst, row_ptr, row_cnt, csr_src, N_EDGES);

    // ---- layer 1 ----
    gemm_fused<<<GB, 256, 0, stream>>>(x, Bp1, as1, ad1, hWb, hs, hd, F_IN);
    attn_agg<<<NW, 256, 0, stream>>>(hWb, hs, hd, row_ptr, csr_src, b1, hA, N_NODES, 1);
    // ---- layer 2 ----
    gemm_fused<<<GB, 256, 0, stream>>>(hA, Bp2, as2, ad2, hWb, hs, hd, H);
    attn_agg<<<NW, 256, 0, stream>>>(hWb, hs, hd, row_ptr, csr_src, b2, hA, N_NODES, 1);
    // ---- layer 3 (no relu) ----
    gemm_fused<<<GB, 256, 0, stream>>>(hA, Bp3, as3, ad3, hWb, hs, hd, H);
    attn_agg<<<NW, 256, 0, stream>>>(hWb, hs, hd, row_ptr, csr_src, b3, hA, N_NODES, 0);

    // ---- head ----
    pool_part<<<NG * 8, H, 0, stream>>>(hA, batch, part, N_NODES);
    fc1_bn_relu<<<NG * 4, 256, 0, stream>>>(part, batch, fc1W, fc1b, bng, bnb, bnrm, bnrv, z, N_NODES);
    fc2_sig<<<NG, 320, 0, stream>>>(z, fc2W, fc2b, (float*)d_out);
}